// Round 4
// baseline (396.577 us; speedup 1.0000x reference)
//
#include <hip/hip_runtime.h>
#include <hip/hip_bf16.h>
#include <stdint.h>

#define N_LEAVES 65536
#define MEM 128
#define HID 128

typedef float  f32x4 __attribute__((ext_vector_type(4)));
typedef short  s16x8 __attribute__((ext_vector_type(8)));
typedef unsigned short u16;

__device__ __forceinline__ u16 f2bf(float x) {
    unsigned u = __builtin_bit_cast(unsigned, x);
    u += 0x7FFFu + ((u >> 16) & 1u);          // round-to-nearest-even
    return (u16)(u >> 16);
}
__device__ __forceinline__ float bf2f(u16 b) {
    unsigned u = ((unsigned)b) << 16;
    return __builtin_bit_cast(float, u);
}
// tanh with full RELATIVE accuracy for small |x|.
__device__ __forceinline__ float tanh_p(float x) {
    float x2 = x * x;
    float poly = x * (1.0f + x2 * (-0.33333334f + x2 * 0.13333334f));
    float E = __builtin_amdgcn_exp2f(x * 2.8853900817779268f);        // exp(2x)
    float ex = 1.0f - 2.0f / (E + 1.0f);
    return (__builtin_fabsf(x) < 0.25f) ? poly : ex;
}

// ---------------- split fp32 -> bf16 hi/lo planes ----------------
__global__ __launch_bounds__(256) void split_kernel(
    const float* __restrict__ src, u16* __restrict__ hi, u16* __restrict__ lo, int n)
{
    int i = blockIdx.x * 256 + threadIdx.x;
    int stride = gridDim.x * 256;
    for (; i < n; i += stride) {
        float x = src[i];
        u16 h = f2bf(x);
        float r = x - bf2f(h);
        hi[i] = h;
        lo[i] = f2bf(r);
    }
}

// LDS swizzle (applied on the READ side; staging pre-swizzles the GLOBAL
// source so the LDS write stays linear — rule #21): 16B granule,
// slot = ch ^ (row&3) ^ ((row>>2)&3)  ->  <=2-way ds_read_b128.
__device__ __forceinline__ int swz(int row, int ch) {
    int slot = (ch ^ (row & 3) ^ ((row >> 2) & 3)) & 3;
    return row * 32 + slot * 8;    // u16 offset; row stride 32 u16 = 64B
}

// async global->LDS, 16B per lane (global_load_lds_dwordx4)
__device__ __forceinline__ void gl_lds16(const void* g, void* l) {
    __builtin_amdgcn_global_load_lds(
        (const __attribute__((address_space(1))) unsigned int*)g,
        (__attribute__((address_space(3))) unsigned int*)l, 16, 0, 0);
}

// ---------------- split-bf16 MFMA GEMM: C = epi(A[M][K] @ W[N][K]^T) ----------------
// EPI=0 leaf: C[m][n] = tanh(dot), hi/lo planes [M][N]
// EPI=1 tree: C[p][n] = 0.25*sum_{r<4} tanh(dot(row 4p+r)), W selected by ops[p]
//             OUTF32=1: write fp32 to Cf instead of hi/lo planes (level 3)
// Requires M % 128 == 0 (all call sites satisfy this).
template<int EPI, int OUTF32>
__global__ __launch_bounds__(256, 2) void gemm_bf(
    const u16* __restrict__ Ah, const u16* __restrict__ Al,
    const u16* __restrict__ B0h, const u16* __restrict__ B0l,
    const u16* __restrict__ B1h, const u16* __restrict__ B1l,
    const int* __restrict__ ops,
    u16* __restrict__ Ch, u16* __restrict__ Cl, float* __restrict__ Cf,
    int M, int N, int K)
{
    __shared__ u16 sAh[2][4096], sAl[2][4096], sBh[2][4096], sBl[2][4096];
    __shared__ u16 sB2h[2][EPI ? 4096 : 8], sB2l[2][EPI ? 4096 : 8];

    const int tid = threadIdx.x;
    const int l   = tid & 63;
    const int w   = tid >> 6;
    const int wm  = w >> 1, wn = w & 1;
    const int lr  = l & 15, lc = l >> 4;
    const int bm  = blockIdx.x * 128;
    const int bn  = blockIdx.y * 128;

    // staging: segment seg = w*2+c covers granules [seg*64, seg*64+64);
    // lane fills granule g = seg*64 + l linearly in LDS; the global chunk
    // index is the inverse swizzle so that reads with swz() see tile order.
    int rows[2], chs[2];
    #pragma unroll
    for (int c = 0; c < 2; ++c) {
        int g = (w * 2 + c) * 64 + l;
        int row = g >> 2;
        rows[c] = row;
        chs[c]  = (g & 3) ^ (row & 3) ^ ((row >> 2) & 3);
    }

    auto stage = [&](int buf, int k0) {
        #pragma unroll
        for (int c = 0; c < 2; ++c) {
            const int row = rows[c], ch = chs[c];
            const int segoff = (w * 2 + c) * 512;
            size_t ga = (size_t)(bm + row) * K + k0 + ch * 8;
            size_t gb = (size_t)(bn + row) * K + k0 + ch * 8;
            gl_lds16(Ah  + ga, &sAh[buf][segoff]);
            gl_lds16(Al  + ga, &sAl[buf][segoff]);
            gl_lds16(B0h + gb, &sBh[buf][segoff]);
            gl_lds16(B0l + gb, &sBl[buf][segoff]);
            if constexpr (EPI) {
                gl_lds16(B1h + gb, &sB2h[buf][segoff]);
                gl_lds16(B1l + gb, &sB2l[buf][segoff]);
            }
        }
    };

    f32x4 acc0[4][4] = {};
    f32x4 acc1[4][4] = {};           // tree only; DCE'd for leaf

    const int nt = K >> 5;
    stage(0, 0);
    __syncthreads();                 // drains vmcnt(0): buf0 ready

    for (int t = 0; t < nt; ++t) {
        const int cur = t & 1;
        if (t + 1 < nt) stage(cur ^ 1, (t + 1) << 5);

        s16x8 fah[4], fal[4];
        #pragma unroll
        for (int mi = 0; mi < 4; ++mi) {
            int so = swz(wm * 64 + mi * 16 + lr, lc);
            fah[mi] = *(const s16x8*)&sAh[cur][so];
            fal[mi] = *(const s16x8*)&sAl[cur][so];
        }

        if constexpr (!EPI) {
            s16x8 fbh[4], fbl[4];
            #pragma unroll
            for (int nj = 0; nj < 4; ++nj) {
                int so = swz(wn * 64 + nj * 16 + lr, lc);
                fbh[nj] = *(const s16x8*)&sBh[cur][so];
                fbl[nj] = *(const s16x8*)&sBl[cur][so];
            }
            #pragma unroll
            for (int mi = 0; mi < 4; ++mi)
                #pragma unroll
                for (int nj = 0; nj < 4; ++nj) {
                    f32x4 a = acc0[mi][nj];
                    a = __builtin_amdgcn_mfma_f32_16x16x32_bf16(fah[mi], fbh[nj], a, 0, 0, 0);
                    a = __builtin_amdgcn_mfma_f32_16x16x32_bf16(fah[mi], fbl[nj], a, 0, 0, 0);
                    a = __builtin_amdgcn_mfma_f32_16x16x32_bf16(fal[mi], fbh[nj], a, 0, 0, 0);
                    acc0[mi][nj] = a;
                }
        } else {
            #pragma unroll
            for (int nj = 0; nj < 4; ++nj) {
                int so = swz(wn * 64 + nj * 16 + lr, lc);
                s16x8 b0h = *(const s16x8*)&sBh[cur][so];
                s16x8 b0l = *(const s16x8*)&sBl[cur][so];
                s16x8 b1h = *(const s16x8*)&sB2h[cur][so];
                s16x8 b1l = *(const s16x8*)&sB2l[cur][so];
                #pragma unroll
                for (int mi = 0; mi < 4; ++mi) {
                    f32x4 a = acc0[mi][nj];
                    a = __builtin_amdgcn_mfma_f32_16x16x32_bf16(fah[mi], b0h, a, 0, 0, 0);
                    a = __builtin_amdgcn_mfma_f32_16x16x32_bf16(fah[mi], b0l, a, 0, 0, 0);
                    a = __builtin_amdgcn_mfma_f32_16x16x32_bf16(fal[mi], b0h, a, 0, 0, 0);
                    acc0[mi][nj] = a;
                    f32x4 o = acc1[mi][nj];
                    o = __builtin_amdgcn_mfma_f32_16x16x32_bf16(fah[mi], b1h, o, 0, 0, 0);
                    o = __builtin_amdgcn_mfma_f32_16x16x32_bf16(fah[mi], b1l, o, 0, 0, 0);
                    o = __builtin_amdgcn_mfma_f32_16x16x32_bf16(fal[mi], b1h, o, 0, 0, 0);
                    acc1[mi][nj] = o;
                }
            }
        }
        __syncthreads();   // drains prefetch vmcnt + protects buffer reuse
    }

    if constexpr (!EPI) {
        #pragma unroll
        for (int mi = 0; mi < 4; ++mi)
            #pragma unroll
            for (int nj = 0; nj < 4; ++nj) {
                int col = bn + wn * 64 + nj * 16 + lr;
                f32x4 v = acc0[mi][nj];
                #pragma unroll
                for (int r = 0; r < 4; ++r) {
                    int m = bm + wm * 64 + mi * 16 + lc * 4 + r;
                    float t = tanh_p(v[r]);
                    u16 hb = f2bf(t);
                    float lo = t - bf2f(hb);
                    size_t g = (size_t)m * N + col;
                    Ch[g] = hb;
                    Cl[g] = f2bf(lo);
                }
            }
    } else {
        #pragma unroll
        for (int mi = 0; mi < 4; ++mi) {
            int p = (bm >> 2) + wm * 16 + mi * 4 + lc;   // lane's 4 D-rows = one parent
            int op = ops[p];
            #pragma unroll
            for (int nj = 0; nj < 4; ++nj) {
                int col = wn * 64 + nj * 16 + lr;
                f32x4 v = op ? acc1[mi][nj] : acc0[mi][nj];
                float t = 0.25f * (tanh_p(v[0]) + tanh_p(v[1]) + tanh_p(v[2]) + tanh_p(v[3]));
                size_t g = (size_t)p * 128 + col;
                if constexpr (OUTF32) {
                    Cf[g] = t;
                } else {
                    u16 hb = f2bf(t);
                    float lo = t - bf2f(hb);
                    Ch[g] = hb;
                    Cl[g] = f2bf(lo);
                }
            }
        }
    }
}

// ---------------- fused tail: tree levels 2,1,0 + readout (fp32) ----------------
__global__ __launch_bounds__(256) void tail_kernel(
    const float* __restrict__ h3,     // [64][128] level-3 output
    const int* __restrict__ ops,
    const float* __restrict__ Wand, const float* __restrict__ Wor,
    const float* __restrict__ Rw1, const float* __restrict__ Rb1,
    const float* __restrict__ Rw2, const float* __restrict__ Rb2,
    const float* __restrict__ Rw3, const float* __restrict__ Rb3,
    const float* __restrict__ Rwp, const float* __restrict__ Rbp,
    float* __restrict__ out)
{
    __shared__ float H[64 * 128];
    __shared__ float O[16 * 128];
    const int tid = threadIdx.x;

    for (int i = tid; i < 64 * 128; i += 256) H[i] = h3[i];
    __syncthreads();

    // level 2: 16 parents (ops base 5)
    for (int idx = tid; idx < 16 * 128; idx += 256) {
        int p = idx >> 7, o = idx & 127;
        const float* Wsel = (ops[5 + p] == 0) ? Wand : Wor;
        float s = 0.f;
        for (int c = 0; c < 4; ++c) {
            float d = 0.f;
            const float* hr = &H[(p * 4 + c) * 128];
            for (int m = 0; m < 128; ++m) d = fmaf(Wsel[o * 128 + m], hr[m], d);
            s += tanh_p(d);
        }
        O[idx] = 0.25f * s;
    }
    __syncthreads();
    for (int i = tid; i < 16 * 128; i += 256) H[i] = O[i];
    __syncthreads();

    // level 1: 4 parents (ops base 1)
    for (int idx = tid; idx < 4 * 128; idx += 256) {
        int p = idx >> 7, o = idx & 127;
        const float* Wsel = (ops[1 + p] == 0) ? Wand : Wor;
        float s = 0.f;
        for (int c = 0; c < 4; ++c) {
            float d = 0.f;
            const float* hr = &H[(p * 4 + c) * 128];
            for (int m = 0; m < 128; ++m) d = fmaf(Wsel[o * 128 + m], hr[m], d);
            s += tanh_p(d);
        }
        O[idx] = 0.25f * s;
    }
    __syncthreads();
    for (int i = tid; i < 4 * 128; i += 256) H[i] = O[i];
    __syncthreads();

    // level 0: root (ops base 0)
    if (tid < 128) {
        int o = tid;
        const float* Wsel = (ops[0] == 0) ? Wand : Wor;
        float s = 0.f;
        for (int c = 0; c < 4; ++c) {
            float d = 0.f;
            const float* hr = &H[c * 128];
            for (int m = 0; m < 128; ++m) d = fmaf(Wsel[o * 128 + m], hr[m], d);
            s += tanh_p(d);
        }
        O[o] = 0.25f * s;
    }
    __syncthreads();

    // readout
    if (tid < 128) {
        int o = tid;
        float s = 0.f;
        for (int m = 0; m < 128; ++m) s = fmaf(Rw1[o * 128 + m], O[m], s);
        H[o] = fmaxf(s + Rb1[o], 0.f);
    }
    __syncthreads();
    if (tid < 128) {
        int o = tid;
        float s = 0.f;
        for (int m = 0; m < 128; ++m) s = fmaf(Rw2[o * 128 + m], H[m], s);
        H[128 + o] = fmaxf(s + Rb2[o], 0.f);
    }
    __syncthreads();
    if (tid < 128) {
        int o = tid;
        float s = 0.f;
        for (int m = 0; m < 128; ++m) s = fmaf(Rw3[o * 128 + m], H[128 + m], s);
        H[256 + o] = fmaxf(s + Rb3[o], 0.f) * Rwp[o];
    }
    __syncthreads();
    if (tid == 0) {
        float t = 0.f;
        for (int i = 0; i < 128; ++i) t += H[256 + i];
        out[0] = t + Rbp[0];
    }
}

// ---------------- host launch ----------------
extern "C" void kernel_launch(void* const* d_in, const int* in_sizes, int n_in,
                              void* d_out, int out_size, void* d_ws, size_t ws_size,
                              hipStream_t stream)
{
    const float* inputs = (const float*)d_in[0];
    const int*   ops    = (const int*)d_in[1];
    const float* W1     = (const float*)d_in[2];
    const float* W2     = (const float*)d_in[3];
    const float* W3     = (const float*)d_in[4];
    const float* Wp     = (const float*)d_in[5];
    const float* Wand   = (const float*)d_in[6];
    const float* Wor    = (const float*)d_in[7];
    const float* Rw1    = (const float*)d_in[8];
    const float* Rb1    = (const float*)d_in[9];
    const float* Rw2    = (const float*)d_in[10];
    const float* Rb2    = (const float*)d_in[11];
    const float* Rw3    = (const float*)d_in[12];
    const float* Rb3    = (const float*)d_in[13];
    const float* Rwp    = (const float*)d_in[14];
    const float* Rbp    = (const float*)d_in[15];
    float* out = (float*)d_out;
    u16* ws = (u16*)d_ws;

    // ---- workspace layout (u16 elements) ----
    size_t off = 0;
    u16* inh = ws + off; off += (size_t)N_LEAVES * 64;
    u16* inl = ws + off; off += (size_t)N_LEAVES * 64;
    u16* w1h = ws + off; off += 8192;   u16* w1l = ws + off; off += 8192;
    u16* w2h = ws + off; off += 49152;  u16* w2l = ws + off; off += 49152;
    u16* w3h = ws + off; off += 98304;  u16* w3l = ws + off; off += 98304;
    u16* wph = ws + off; off += 32768;  u16* wpl = ws + off; off += 32768;
    u16* wah = ws + off; off += 16384;  u16* wal = ws + off; off += 16384;
    u16* woh = ws + off; off += 16384;  u16* wol = ws + off; off += 16384;
    u16* h4h = ws + off; off += (size_t)N_LEAVES * 128;
    u16* h4l = ws + off; off += (size_t)N_LEAVES * 128;
    float* h3f = (float*)(ws + off); off += 16384;   // 8192 floats [64][128]

    const size_t fixed = off;
    // pA: h1 (chunk x 128 x2) / h3 (chunk x 256 x2) / tree even buffers
    // pB: h2 (chunk x 384 x2) / tree odd buffers
    int chunk;
    {
        size_t full  = (fixed + (size_t)N_LEAVES * 512 + (size_t)N_LEAVES * 768) * 2;
        size_t half  = (fixed + (size_t)16384 * 512 + (size_t)16384 * 768) * 2;
        if (ws_size >= full)      chunk = N_LEAVES;
        else if (ws_size >= half) chunk = 16384;
        else                      chunk = 8192;
    }
    u16* pA = ws + fixed;
    u16* pB = pA + (size_t)chunk * 512;

    // ---- split prep ----
    split_kernel<<<1024, 256, 0, stream>>>(inputs, inh, inl, N_LEAVES * 64);
    split_kernel<<<32,  256, 0, stream>>>(W1,  w1h, w1l, 8192);
    split_kernel<<<192, 256, 0, stream>>>(W2,  w2h, w2l, 49152);
    split_kernel<<<384, 256, 0, stream>>>(W3,  w3h, w3l, 98304);
    split_kernel<<<128, 256, 0, stream>>>(Wp,  wph, wpl, 32768);
    split_kernel<<<64,  256, 0, stream>>>(Wand, wah, wal, 16384);
    split_kernel<<<64,  256, 0, stream>>>(Wor,  woh, wol, 16384);

    // ---- leaf MLP ----
    for (int c0 = 0; c0 < N_LEAVES; c0 += chunk) {
        const u16* aH = inh + (size_t)c0 * 64;
        const u16* aL = inl + (size_t)c0 * 64;
        gemm_bf<0,0><<<dim3(chunk / 128, 1), 256, 0, stream>>>(
            aH, aL, w1h, w1l, nullptr, nullptr, nullptr,
            pA, pA + (size_t)chunk * 128, nullptr, chunk, 128, 64);
        gemm_bf<0,0><<<dim3(chunk / 128, 3), 256, 0, stream>>>(
            pA, pA + (size_t)chunk * 128, w2h, w2l, nullptr, nullptr, nullptr,
            pB, pB + (size_t)chunk * 384, nullptr, chunk, 384, 128);
        gemm_bf<0,0><<<dim3(chunk / 128, 2), 256, 0, stream>>>(
            pB, pB + (size_t)chunk * 384, w3h, w3l, nullptr, nullptr, nullptr,
            pA, pA + (size_t)chunk * 256, nullptr, chunk, 256, 384);
        gemm_bf<0,0><<<dim3(chunk / 128, 1), 256, 0, stream>>>(
            pA, pA + (size_t)chunk * 256, wph, wpl, nullptr, nullptr, nullptr,
            h4h + (size_t)c0 * 128, h4l + (size_t)c0 * 128, nullptr, chunk, 128, 256);
    }

    // ---- tree reduction, levels 7..4 (bf16 planes), level 3 (f32 out) ----
    const u16* hinH = h4h;
    const u16* hinL = h4l;
    for (int lv = 7; lv >= 4; --lv) {
        int n = 1 << (2 * lv);
        int start = (n - 1) / 3;
        int Mr = n * 4;
        u16* outH = (lv & 1) ? pB : pA;
        u16* outL = outH + (size_t)n * 128;
        gemm_bf<1,0><<<dim3(Mr / 128, 1), 256, 0, stream>>>(
            hinH, hinL, wah, wal, woh, wol, ops + start,
            outH, outL, nullptr, Mr, 128, 128);
        hinH = outH;
        hinL = outL;
    }
    // level 3: 64 parents, 256 child rows -> f32 h3
    gemm_bf<1,1><<<dim3(2, 1), 256, 0, stream>>>(
        hinH, hinL, wah, wal, woh, wol, ops + 21,
        nullptr, nullptr, h3f, 256, 128, 128);

    // ---- fused tail: levels 2,1,0 + readout ----
    tail_kernel<<<1, 256, 0, stream>>>(h3f, ops, Wand, Wor,
        Rw1, Rb1, Rw2, Rb2, Rw3, Rb3, Rwp, Rbp, out);
}

// Round 5
// 274.995 us; speedup vs baseline: 1.4421x; 1.4421x over previous
//
#include <hip/hip_runtime.h>
#include <hip/hip_bf16.h>
#include <stdint.h>

#define N_LEAVES 65536
#define MEM 128
#define HID 128

typedef float  f32x4 __attribute__((ext_vector_type(4)));
typedef short  s16x8 __attribute__((ext_vector_type(8)));
typedef unsigned short u16;

__device__ __forceinline__ u16 f2bf(float x) {
    unsigned u = __builtin_bit_cast(unsigned, x);
    u += 0x7FFFu + ((u >> 16) & 1u);          // round-to-nearest-even
    return (u16)(u >> 16);
}
__device__ __forceinline__ float bf2f(u16 b) {
    unsigned u = ((unsigned)b) << 16;
    return __builtin_bit_cast(float, u);
}
// tanh with full RELATIVE accuracy for small |x|.
__device__ __forceinline__ float tanh_p(float x) {
    float x2 = x * x;
    float poly = x * (1.0f + x2 * (-0.33333334f + x2 * 0.13333334f));
    float E = __builtin_amdgcn_exp2f(x * 2.8853900817779268f);        // exp(2x)
    float ex = 1.0f - 2.0f / (E + 1.0f);
    return (__builtin_fabsf(x) < 0.25f) ? poly : ex;
}

// ---------------- split fp32 -> bf16 hi/lo planes ----------------
__global__ __launch_bounds__(256) void split_kernel(
    const float* __restrict__ src, u16* __restrict__ hi, u16* __restrict__ lo, int n)
{
    int i = blockIdx.x * 256 + threadIdx.x;
    int stride = gridDim.x * 256;
    for (; i < n; i += stride) {
        float x = src[i];
        u16 h = f2bf(x);
        float r = x - bf2f(h);
        hi[i] = h;
        lo[i] = f2bf(r);
    }
}

// LDS swizzle (applied on the READ side; staging pre-swizzles the GLOBAL
// source so the LDS write stays linear — rule #21): 16B granule,
// slot = ch ^ (row&3) ^ ((row>>2)&3)  ->  <=2-way ds_read_b128.
__device__ __forceinline__ int swz(int row, int ch) {
    int slot = (ch ^ (row & 3) ^ ((row >> 2) & 3)) & 3;
    return row * 32 + slot * 8;    // u16 offset; row stride 32 u16 = 64B
}

// async global->LDS, 16B per lane (global_load_lds_dwordx4)
__device__ __forceinline__ void gl_lds16(const void* g, void* l) {
    __builtin_amdgcn_global_load_lds(
        (const __attribute__((address_space(1))) unsigned int*)g,
        (__attribute__((address_space(3))) unsigned int*)l, 16, 0, 0);
}

// ---------------- split-bf16 MFMA GEMM: C = epi(A[M][K] @ W[N][K]^T) ----------------
// EPI=0 leaf: C[m][n] = tanh(dot), hi/lo planes [M][N]. Requires M%128==0.
//             Double-buffered LDS (64KB), 2 blocks/CU.
// EPI=1 tree: C[p][n] = 0.25*sum_{r<4} tanh(dot(row 4p+r)), W sel by ops[p].
//             Single-buffered LDS (48KB) so 2 blocks/CU still fit; handles
//             M<128 levels via clamped A loads + guarded epilogue.
template<int EPI>
__global__ __launch_bounds__(256, 2) void gemm_bf(
    const u16* __restrict__ Ah, const u16* __restrict__ Al,
    const u16* __restrict__ B0h, const u16* __restrict__ B0l,
    const u16* __restrict__ B1h, const u16* __restrict__ B1l,
    const int* __restrict__ ops,
    u16* __restrict__ Ch, u16* __restrict__ Cl,
    int M, int N, int K)
{
    constexpr int NBUF = EPI ? 1 : 2;
    __shared__ u16 sAh[NBUF][4096], sAl[NBUF][4096];
    __shared__ u16 sBh[NBUF][4096], sBl[NBUF][4096];
    __shared__ u16 sB2h[NBUF][EPI ? 4096 : 8], sB2l[NBUF][EPI ? 4096 : 8];

    const int tid = threadIdx.x;
    const int l   = tid & 63;
    const int w   = tid >> 6;
    const int wm  = w >> 1, wn = w & 1;
    const int lr  = l & 15, lc = l >> 4;
    const int bm  = blockIdx.x * 128;
    const int bn  = blockIdx.y * 128;

    const int Arows = (M - bm < 128) ? (M - bm) : 128;

    // staging: lane fills granule g = (w*2+c)*64 + l linearly in LDS; the
    // global chunk index carries the inverse swizzle so reads see tile order.
    int rows[2], chs[2];
    #pragma unroll
    for (int c = 0; c < 2; ++c) {
        int g = (w * 2 + c) * 64 + l;
        int row = g >> 2;
        rows[c] = row;
        chs[c]  = (g & 3) ^ (row & 3) ^ ((row >> 2) & 3);
    }

    auto stage = [&](int buf, int k0) {
        #pragma unroll
        for (int c = 0; c < 2; ++c) {
            const int row = rows[c], ch = chs[c];
            const int ra  = (row < Arows) ? row : (Arows - 1);   // clamp (tree tails)
            const int segoff = (w * 2 + c) * 512;
            size_t ga = (size_t)(bm + ra) * K + k0 + ch * 8;
            size_t gb = (size_t)(bn + row) * K + k0 + ch * 8;
            gl_lds16(Ah  + ga, &sAh[buf][segoff]);
            gl_lds16(Al  + ga, &sAl[buf][segoff]);
            gl_lds16(B0h + gb, &sBh[buf][segoff]);
            gl_lds16(B0l + gb, &sBl[buf][segoff]);
            if constexpr (EPI) {
                gl_lds16(B1h + gb, &sB2h[buf][segoff]);
                gl_lds16(B1l + gb, &sB2l[buf][segoff]);
            }
        }
    };

    f32x4 acc0[4][4] = {};
    f32x4 acc1[4][4] = {};           // tree only; DCE'd for leaf

    const int nt = K >> 5;
    if constexpr (!EPI) { stage(0, 0); __syncthreads(); }

    for (int t = 0; t < nt; ++t) {
        int cur;
        if constexpr (!EPI) {
            cur = t & 1;
            if (t + 1 < nt) stage(cur ^ 1, (t + 1) << 5);
        } else {
            cur = 0;
            stage(0, t << 5);
            __syncthreads();         // drain vmcnt: buffer ready
        }

        s16x8 fah[4], fal[4];
        #pragma unroll
        for (int mi = 0; mi < 4; ++mi) {
            int so = swz(wm * 64 + mi * 16 + lr, lc);
            fah[mi] = *(const s16x8*)&sAh[cur][so];
            fal[mi] = *(const s16x8*)&sAl[cur][so];
        }

        if constexpr (!EPI) {
            s16x8 fbh[4], fbl[4];
            #pragma unroll
            for (int nj = 0; nj < 4; ++nj) {
                int so = swz(wn * 64 + nj * 16 + lr, lc);
                fbh[nj] = *(const s16x8*)&sBh[cur][so];
                fbl[nj] = *(const s16x8*)&sBl[cur][so];
            }
            #pragma unroll
            for (int mi = 0; mi < 4; ++mi)
                #pragma unroll
                for (int nj = 0; nj < 4; ++nj) {
                    f32x4 a = acc0[mi][nj];
                    a = __builtin_amdgcn_mfma_f32_16x16x32_bf16(fah[mi], fbh[nj], a, 0, 0, 0);
                    a = __builtin_amdgcn_mfma_f32_16x16x32_bf16(fah[mi], fbl[nj], a, 0, 0, 0);
                    a = __builtin_amdgcn_mfma_f32_16x16x32_bf16(fal[mi], fbh[nj], a, 0, 0, 0);
                    acc0[mi][nj] = a;
                }
        } else {
            #pragma unroll
            for (int nj = 0; nj < 4; ++nj) {
                int so = swz(wn * 64 + nj * 16 + lr, lc);
                s16x8 b0h = *(const s16x8*)&sBh[cur][so];
                s16x8 b0l = *(const s16x8*)&sBl[cur][so];
                s16x8 b1h = *(const s16x8*)&sB2h[cur][so];
                s16x8 b1l = *(const s16x8*)&sB2l[cur][so];
                #pragma unroll
                for (int mi = 0; mi < 4; ++mi) {
                    f32x4 a = acc0[mi][nj];
                    a = __builtin_amdgcn_mfma_f32_16x16x32_bf16(fah[mi], b0h, a, 0, 0, 0);
                    a = __builtin_amdgcn_mfma_f32_16x16x32_bf16(fah[mi], b0l, a, 0, 0, 0);
                    a = __builtin_amdgcn_mfma_f32_16x16x32_bf16(fal[mi], b0h, a, 0, 0, 0);
                    acc0[mi][nj] = a;
                    f32x4 o = acc1[mi][nj];
                    o = __builtin_amdgcn_mfma_f32_16x16x32_bf16(fah[mi], b1h, o, 0, 0, 0);
                    o = __builtin_amdgcn_mfma_f32_16x16x32_bf16(fah[mi], b1l, o, 0, 0, 0);
                    o = __builtin_amdgcn_mfma_f32_16x16x32_bf16(fal[mi], b1h, o, 0, 0, 0);
                    acc1[mi][nj] = o;
                }
            }
        }
        __syncthreads();   // dbuf: drain prefetch + protect reuse | single: protect overwrite
    }

    if constexpr (!EPI) {
        #pragma unroll
        for (int mi = 0; mi < 4; ++mi)
            #pragma unroll
            for (int nj = 0; nj < 4; ++nj) {
                int col = bn + wn * 64 + nj * 16 + lr;
                f32x4 v = acc0[mi][nj];
                #pragma unroll
                for (int r = 0; r < 4; ++r) {
                    int m = bm + wm * 64 + mi * 16 + lc * 4 + r;
                    float t = tanh_p(v[r]);
                    u16 hb = f2bf(t);
                    float lo = t - bf2f(hb);
                    size_t g = (size_t)m * N + col;
                    Ch[g] = hb;
                    Cl[g] = f2bf(lo);
                }
            }
    } else {
        const int P = M >> 2;
        #pragma unroll
        for (int mi = 0; mi < 4; ++mi) {
            int p = (bm >> 2) + wm * 16 + mi * 4 + lc;   // lane's 4 D-rows = one parent
            int pc = (p < P) ? p : (P - 1);
            int op = ops[pc];
            if (p < P) {
                #pragma unroll
                for (int nj = 0; nj < 4; ++nj) {
                    int col = wn * 64 + nj * 16 + lr;
                    f32x4 v = op ? acc1[mi][nj] : acc0[mi][nj];
                    float t = 0.25f * (tanh_p(v[0]) + tanh_p(v[1]) + tanh_p(v[2]) + tanh_p(v[3]));
                    u16 hb = f2bf(t);
                    float lo = t - bf2f(hb);
                    size_t g = (size_t)p * 128 + col;
                    Ch[g] = hb;
                    Cl[g] = f2bf(lo);
                }
            }
        }
    }
}

// ---------------- readout: 1x128 -> relu mlp -> scalar ----------------
__global__ __launch_bounds__(128) void readout_kernel(
    const u16* __restrict__ hH, const u16* __restrict__ hL,
    const float* __restrict__ Rw1, const float* __restrict__ Rb1,
    const float* __restrict__ Rw2, const float* __restrict__ Rb2,
    const float* __restrict__ Rw3, const float* __restrict__ Rb3,
    const float* __restrict__ Rwp, const float* __restrict__ Rbp,
    float* __restrict__ out)
{
    __shared__ float x0[HID], x1[HID], x2[HID], x3[HID], red[HID];
    const int o = threadIdx.x;

    x0[o] = bf2f(hH[o]) + bf2f(hL[o]);
    __syncthreads();

    float s = 0.f;
    for (int m = 0; m < HID; ++m) s += Rw1[o * HID + m] * x0[m];
    x1[o] = fmaxf(s + Rb1[o], 0.f);
    __syncthreads();

    s = 0.f;
    for (int m = 0; m < HID; ++m) s += Rw2[o * HID + m] * x1[m];
    x2[o] = fmaxf(s + Rb2[o], 0.f);
    __syncthreads();

    s = 0.f;
    for (int m = 0; m < HID; ++m) s += Rw3[o * HID + m] * x2[m];
    x3[o] = fmaxf(s + Rb3[o], 0.f);
    __syncthreads();

    red[o] = Rwp[o] * x3[o];
    __syncthreads();
    if (o < 64) red[o] += red[o + 64];
    __syncthreads();
    if (o == 0) {
        float t = 0.f;
        for (int i = 0; i < 64; ++i) t += red[i];
        out[0] = t + Rbp[0];
    }
}

// ---------------- host launch ----------------
extern "C" void kernel_launch(void* const* d_in, const int* in_sizes, int n_in,
                              void* d_out, int out_size, void* d_ws, size_t ws_size,
                              hipStream_t stream)
{
    const float* inputs = (const float*)d_in[0];
    const int*   ops    = (const int*)d_in[1];
    const float* W1     = (const float*)d_in[2];
    const float* W2     = (const float*)d_in[3];
    const float* W3     = (const float*)d_in[4];
    const float* Wp     = (const float*)d_in[5];
    const float* Wand   = (const float*)d_in[6];
    const float* Wor    = (const float*)d_in[7];
    const float* Rw1    = (const float*)d_in[8];
    const float* Rb1    = (const float*)d_in[9];
    const float* Rw2    = (const float*)d_in[10];
    const float* Rb2    = (const float*)d_in[11];
    const float* Rw3    = (const float*)d_in[12];
    const float* Rb3    = (const float*)d_in[13];
    const float* Rwp    = (const float*)d_in[14];
    const float* Rbp    = (const float*)d_in[15];
    float* out = (float*)d_out;
    u16* ws = (u16*)d_ws;

    // ---- workspace layout (u16 elements) ----
    size_t off = 0;
    u16* inh = ws + off; off += (size_t)N_LEAVES * 64;
    u16* inl = ws + off; off += (size_t)N_LEAVES * 64;
    u16* w1h = ws + off; off += 8192;   u16* w1l = ws + off; off += 8192;
    u16* w2h = ws + off; off += 49152;  u16* w2l = ws + off; off += 49152;
    u16* w3h = ws + off; off += 98304;  u16* w3l = ws + off; off += 98304;
    u16* wph = ws + off; off += 32768;  u16* wpl = ws + off; off += 32768;
    u16* wah = ws + off; off += 16384;  u16* wal = ws + off; off += 16384;
    u16* woh = ws + off; off += 16384;  u16* wol = ws + off; off += 16384;
    u16* h4h = ws + off; off += (size_t)N_LEAVES * 128;
    u16* h4l = ws + off; off += (size_t)N_LEAVES * 128;

    const size_t fixed = off;
    // pA: h1 (chunk x 128 x2) / h3 (chunk x 256 x2) / tree even buffers
    // pB: h2 (chunk x 384 x2) / tree odd buffers
    int chunk;
    {
        size_t full  = (fixed + (size_t)N_LEAVES * 512 + (size_t)N_LEAVES * 768) * 2;
        size_t half  = (fixed + (size_t)16384 * 512 + (size_t)16384 * 768) * 2;
        if (ws_size >= full)      chunk = N_LEAVES;
        else if (ws_size >= half) chunk = 16384;
        else                      chunk = 8192;
    }
    u16* pA = ws + fixed;
    u16* pB = pA + (size_t)chunk * 512;

    // ---- split prep ----
    split_kernel<<<1024, 256, 0, stream>>>(inputs, inh, inl, N_LEAVES * 64);
    split_kernel<<<32,  256, 0, stream>>>(W1,  w1h, w1l, 8192);
    split_kernel<<<192, 256, 0, stream>>>(W2,  w2h, w2l, 49152);
    split_kernel<<<384, 256, 0, stream>>>(W3,  w3h, w3l, 98304);
    split_kernel<<<128, 256, 0, stream>>>(Wp,  wph, wpl, 32768);
    split_kernel<<<64,  256, 0, stream>>>(Wand, wah, wal, 16384);
    split_kernel<<<64,  256, 0, stream>>>(Wor,  woh, wol, 16384);

    // ---- leaf MLP ----
    for (int c0 = 0; c0 < N_LEAVES; c0 += chunk) {
        const u16* aH = inh + (size_t)c0 * 64;
        const u16* aL = inl + (size_t)c0 * 64;
        gemm_bf<0><<<dim3(chunk / 128, 1), 256, 0, stream>>>(
            aH, aL, w1h, w1l, nullptr, nullptr, nullptr,
            pA, pA + (size_t)chunk * 128, chunk, 128, 64);
        gemm_bf<0><<<dim3(chunk / 128, 3), 256, 0, stream>>>(
            pA, pA + (size_t)chunk * 128, w2h, w2l, nullptr, nullptr, nullptr,
            pB, pB + (size_t)chunk * 384, chunk, 384, 128);
        gemm_bf<0><<<dim3(chunk / 128, 2), 256, 0, stream>>>(
            pB, pB + (size_t)chunk * 384, w3h, w3l, nullptr, nullptr, nullptr,
            pA, pA + (size_t)chunk * 256, chunk, 256, 384);
        gemm_bf<0><<<dim3(chunk / 128, 1), 256, 0, stream>>>(
            pA, pA + (size_t)chunk * 256, wph, wpl, nullptr, nullptr, nullptr,
            h4h + (size_t)c0 * 128, h4l + (size_t)c0 * 128, chunk, 128, 256);
    }

    // ---- tree reduction, level 7 down to 0 ----
    const u16* hinH = h4h;
    const u16* hinL = h4l;
    for (int lv = 7; lv >= 0; --lv) {
        int n = 1 << (2 * lv);
        int start = (n - 1) / 3;
        int Mr = n * 4;
        u16* outH = (lv & 1) ? pB : pA;
        u16* outL = outH + (size_t)n * 128;
        gemm_bf<1><<<dim3((Mr + 127) / 128, 1), 256, 0, stream>>>(
            hinH, hinL, wah, wal, woh, wol, ops + start,
            outH, outL, Mr, 128, 128);
        hinH = outH;
        hinL = outL;
    }

    // ---- readout ----
    readout_kernel<<<1, 128, 0, stream>>>(hinH, hinL,
        Rw1, Rb1, Rw2, Rb2, Rw3, Rb3, Rwp, Rbp, out);
}

// Round 6
// 224.656 us; speedup vs baseline: 1.7653x; 1.2241x over previous
//
#include <hip/hip_runtime.h>
#include <hip/hip_bf16.h>
#include <stdint.h>

#define N_LEAVES 65536
#define MEM 128
#define HID 128

typedef float  f32x4 __attribute__((ext_vector_type(4)));
typedef short  s16x8 __attribute__((ext_vector_type(8)));
typedef unsigned short u16;

__device__ __forceinline__ u16 f2bf(float x) {
    unsigned u = __builtin_bit_cast(unsigned, x);
    u += 0x7FFFu + ((u >> 16) & 1u);          // round-to-nearest-even
    return (u16)(u >> 16);
}
__device__ __forceinline__ float bf2f(u16 b) {
    unsigned u = ((unsigned)b) << 16;
    return __builtin_bit_cast(float, u);
}
// tanh with full RELATIVE accuracy for small |x|.
__device__ __forceinline__ float tanh_p(float x) {
    float x2 = x * x;
    float poly = x * (1.0f + x2 * (-0.33333334f + x2 * 0.13333334f));
    float E = __builtin_amdgcn_exp2f(x * 2.8853900817779268f);        // exp(2x)
    float ex = 1.0f - 2.0f / (E + 1.0f);
    return (__builtin_fabsf(x) < 0.25f) ? poly : ex;
}

__device__ __forceinline__ f32x4 mfma_bf(s16x8 a, s16x8 b, f32x4 c) {
    return __builtin_amdgcn_mfma_f32_16x16x32_bf16(a, b, c, 0, 0, 0);
}

// ---------------- split fp32 -> bf16 hi/lo planes (row-major, for tree W) ----
__global__ __launch_bounds__(256) void split_kernel(
    const float* __restrict__ src, u16* __restrict__ hi, u16* __restrict__ lo, int n)
{
    int i = blockIdx.x * 256 + threadIdx.x;
    int stride = gridDim.x * 256;
    for (; i < n; i += stride) {
        float x = src[i];
        u16 h = f2bf(x);
        float r = x - bf2f(h);
        hi[i] = h;
        lo[i] = f2bf(r);
    }
}

// ---------------- split fp32 W[N][K] -> k-major fragment layout hi/lo --------
// Th/Tl layout: [(kg)*N + n]*8 + j  where kg = k/8, j = k%8.
// A B-fragment load for (colBase+nj*16+lr, kt, lc) is then 16B contiguous
// per lane and coalesced across the 16-lane group.
__global__ __launch_bounds__(256) void wsplit_t(
    const float* __restrict__ W, u16* __restrict__ Th, u16* __restrict__ Tl,
    int N, int K)
{
    int idx = blockIdx.x * 256 + threadIdx.x;   // one granule (8 elems)
    int total = N * (K >> 3);
    if (idx >= total) return;
    int n  = idx / (K >> 3);
    int cg = idx - n * (K >> 3);
    const float* src = &W[(size_t)n * K + cg * 8];
    size_t dst = ((size_t)cg * N + n) * 8;
    #pragma unroll
    for (int j = 0; j < 8; ++j) {
        float v = src[j];
        u16 hb = f2bf(v);
        Th[dst + j] = hb;
        Tl[dst + j] = f2bf(v - bf2f(hb));
    }
}

// act LDS addressing: 16B granules, XOR-swizzled within each row's 8-granule
// stripe -> A-frag ds_read_b128 and epilogue writes are <=2-way conflicts.
// Wu = row width in u16 (multiple of 64 -> granules/row multiple of 8).
__device__ __forceinline__ int act_g(int Wu, int row, int c4) {
    return row * (Wu >> 3) + (c4 ^ (row & 7));   // granule index
}

// ---------------- one fused MLP layer (32 rows, 4 waves split over cols) ----
// NJ: 16-col frags per wave; KTN: K/32; WIN/WOUT: in/out width (u16 elems).
template<int NJ, int KTN, int WIN, int WOUT, bool TOGLOBAL>
__device__ __forceinline__ void mlp_layer(
    const u16* inH, const u16* inL,              // LDS planes (swizzled)
    const u16* __restrict__ BtH, const u16* __restrict__ BtL,  // global k-major
    u16* outH, u16* outL,                        // LDS planes or global planes
    int gRowBase, int w, int l)
{
    const int lr = l & 15, lc = l >> 4;
    const int colBase = w * (NJ * 16);

    f32x4 acc[2][NJ] = {};
    s16x8 bh[2][NJ], bl[2][NJ];

    // preload kt=0 B fragments
    #pragma unroll
    for (int nj = 0; nj < NJ; ++nj) {
        size_t o = ((size_t)lc * WOUT + colBase + nj * 16 + lr) * 8;
        bh[0][nj] = *(const s16x8*)&BtH[o];
        bl[0][nj] = *(const s16x8*)&BtL[o];
    }

    #pragma unroll
    for (int kt = 0; kt < KTN; ++kt) {
        const int cur = kt & 1;
        if (kt + 1 < KTN) {
            #pragma unroll
            for (int nj = 0; nj < NJ; ++nj) {
                size_t o = ((size_t)((kt + 1) * 4 + lc) * WOUT + colBase + nj * 16 + lr) * 8;
                bh[cur ^ 1][nj] = *(const s16x8*)&BtH[o];
                bl[cur ^ 1][nj] = *(const s16x8*)&BtL[o];
            }
        }
        s16x8 ah[2], al[2];
        #pragma unroll
        for (int mi = 0; mi < 2; ++mi) {
            int off = act_g(WIN, mi * 16 + lr, kt * 4 + lc) * 8;
            ah[mi] = *(const s16x8*)&inH[off];
            al[mi] = *(const s16x8*)&inL[off];
        }
        #pragma unroll
        for (int mi = 0; mi < 2; ++mi)
            #pragma unroll
            for (int nj = 0; nj < NJ; ++nj) {
                f32x4 a = acc[mi][nj];
                a = mfma_bf(ah[mi], bh[cur][nj], a);
                a = mfma_bf(ah[mi], bl[cur][nj], a);
                a = mfma_bf(al[mi], bh[cur][nj], a);
                acc[mi][nj] = a;
            }
    }

    // epilogue: tanh + re-split + store
    #pragma unroll
    for (int mi = 0; mi < 2; ++mi)
        #pragma unroll
        for (int nj = 0; nj < NJ; ++nj) {
            int col = colBase + nj * 16 + lr;
            f32x4 v = acc[mi][nj];
            #pragma unroll
            for (int r = 0; r < 4; ++r) {
                int row = mi * 16 + lc * 4 + r;
                float t = tanh_p(v[r]);
                u16 hb = f2bf(t);
                u16 lb = f2bf(t - bf2f(hb));
                if constexpr (TOGLOBAL) {
                    size_t g = (size_t)(gRowBase + row) * WOUT + col;
                    outH[g] = hb;
                    outL[g] = lb;
                } else {
                    int go = act_g(WOUT, row, col >> 3) * 8 + (col & 7);
                    outH[go] = hb;
                    outL[go] = lb;
                }
            }
        }
}

// ---------------- fused 4-layer leaf MLP: 32 rows/block ----------------
__global__ __launch_bounds__(256, 2) void leaf_fused(
    const float* __restrict__ x,                 // [65536][64] fp32
    const u16* __restrict__ W1tH, const u16* __restrict__ W1tL,
    const u16* __restrict__ W2tH, const u16* __restrict__ W2tL,
    const u16* __restrict__ W3tH, const u16* __restrict__ W3tL,
    const u16* __restrict__ WptH, const u16* __restrict__ WptL,
    u16* __restrict__ h4H, u16* __restrict__ h4L)
{
    __shared__ u16 buf0[2 * 32 * 384];   // x (64) then h2 (384)
    __shared__ u16 buf1[2 * 32 * 256];   // h1 (128) then h3 (256)

    const int tid = threadIdx.x;
    const int w = tid >> 6, l = tid & 63;
    const int rowBase = blockIdx.x * 32;

    // stage x -> buf0 hi/lo planes (W=64), swizzled
    {
        int row = tid >> 3;
        int c0  = (tid & 7) * 8;
        const float* src = &x[(size_t)(rowBase + row) * 64 + c0];
        float4 v0 = *(const float4*)src;
        float4 v1 = *(const float4*)(src + 4);
        float xs[8] = {v0.x, v0.y, v0.z, v0.w, v1.x, v1.y, v1.z, v1.w};
        int go = act_g(64, row, c0 >> 3) * 8;
        #pragma unroll
        for (int j = 0; j < 8; ++j) {
            u16 hb = f2bf(xs[j]);
            buf0[go + j] = hb;
            buf0[32 * 64 + go + j] = f2bf(xs[j] - bf2f(hb));
        }
    }
    __syncthreads();

    // L1: 64 -> 128
    mlp_layer<2, 2, 64, 128, false>(buf0, buf0 + 32 * 64, W1tH, W1tL,
                                    buf1, buf1 + 32 * 128, 0, w, l);
    __syncthreads();
    // L2: 128 -> 384
    mlp_layer<6, 4, 128, 384, false>(buf1, buf1 + 32 * 128, W2tH, W2tL,
                                     buf0, buf0 + 32 * 384, 0, w, l);
    __syncthreads();
    // L3: 384 -> 256
    mlp_layer<4, 12, 384, 256, false>(buf0, buf0 + 32 * 384, W3tH, W3tL,
                                      buf1, buf1 + 32 * 256, 0, w, l);
    __syncthreads();
    // L4: 256 -> 128, straight to global h4 planes
    mlp_layer<2, 8, 256, 128, true>(buf1, buf1 + 32 * 256, WptH, WptL,
                                    h4H, h4L, rowBase, w, l);
}

// ---------------- tree GEMM (proven round-5 path) ----------------
__device__ __forceinline__ int swz(int row, int ch) {
    int slot = (ch ^ (row & 3) ^ ((row >> 2) & 3)) & 3;
    return row * 32 + slot * 8;
}
__device__ __forceinline__ void gl_lds16(const void* g, void* l) {
    __builtin_amdgcn_global_load_lds(
        (const __attribute__((address_space(1))) unsigned int*)g,
        (__attribute__((address_space(3))) unsigned int*)l, 16, 0, 0);
}

__global__ __launch_bounds__(256, 2) void tree_gemm(
    const u16* __restrict__ Ah, const u16* __restrict__ Al,
    const u16* __restrict__ B0h, const u16* __restrict__ B0l,
    const u16* __restrict__ B1h, const u16* __restrict__ B1l,
    const int* __restrict__ ops,
    u16* __restrict__ Ch, u16* __restrict__ Cl,
    int M, int N, int K)
{
    __shared__ u16 sAh[4096], sAl[4096], sBh[4096], sBl[4096];
    __shared__ u16 sB2h[4096], sB2l[4096];

    const int tid = threadIdx.x;
    const int l   = tid & 63;
    const int w   = tid >> 6;
    const int wm  = w >> 1, wn = w & 1;
    const int lr  = l & 15, lc = l >> 4;
    const int bm  = blockIdx.x * 128;
    const int bn  = blockIdx.y * 128;

    const int Arows = (M - bm < 128) ? (M - bm) : 128;

    int rows[2], chs[2];
    #pragma unroll
    for (int c = 0; c < 2; ++c) {
        int g = (w * 2 + c) * 64 + l;
        int row = g >> 2;
        rows[c] = row;
        chs[c]  = (g & 3) ^ (row & 3) ^ ((row >> 2) & 3);
    }

    f32x4 acc0[4][4] = {};
    f32x4 acc1[4][4] = {};

    const int nt = K >> 5;
    for (int t = 0; t < nt; ++t) {
        #pragma unroll
        for (int c = 0; c < 2; ++c) {
            const int row = rows[c], ch = chs[c];
            const int ra  = (row < Arows) ? row : (Arows - 1);
            const int segoff = (w * 2 + c) * 512;
            size_t ga = (size_t)(bm + ra) * K + (t << 5) + ch * 8;
            size_t gb = (size_t)(bn + row) * K + (t << 5) + ch * 8;
            gl_lds16(Ah  + ga, &sAh[segoff]);
            gl_lds16(Al  + ga, &sAl[segoff]);
            gl_lds16(B0h + gb, &sBh[segoff]);
            gl_lds16(B0l + gb, &sBl[segoff]);
            gl_lds16(B1h + gb, &sB2h[segoff]);
            gl_lds16(B1l + gb, &sB2l[segoff]);
        }
        __syncthreads();

        s16x8 fah[4], fal[4];
        #pragma unroll
        for (int mi = 0; mi < 4; ++mi) {
            int so = swz(wm * 64 + mi * 16 + lr, lc);
            fah[mi] = *(const s16x8*)&sAh[so];
            fal[mi] = *(const s16x8*)&sAl[so];
        }
        #pragma unroll
        for (int nj = 0; nj < 4; ++nj) {
            int so = swz(wn * 64 + nj * 16 + lr, lc);
            s16x8 b0h = *(const s16x8*)&sBh[so];
            s16x8 b0l = *(const s16x8*)&sBl[so];
            s16x8 b1h = *(const s16x8*)&sB2h[so];
            s16x8 b1l = *(const s16x8*)&sB2l[so];
            #pragma unroll
            for (int mi = 0; mi < 4; ++mi) {
                f32x4 a = acc0[mi][nj];
                a = mfma_bf(fah[mi], b0h, a);
                a = mfma_bf(fah[mi], b0l, a);
                a = mfma_bf(fal[mi], b0h, a);
                acc0[mi][nj] = a;
                f32x4 o = acc1[mi][nj];
                o = mfma_bf(fah[mi], b1h, o);
                o = mfma_bf(fah[mi], b1l, o);
                o = mfma_bf(fal[mi], b1h, o);
                acc1[mi][nj] = o;
            }
        }
        __syncthreads();
    }

    const int P = M >> 2;
    #pragma unroll
    for (int mi = 0; mi < 4; ++mi) {
        int p = (bm >> 2) + wm * 16 + mi * 4 + lc;
        int pc = (p < P) ? p : (P - 1);
        int op = ops[pc];
        if (p < P) {
            #pragma unroll
            for (int nj = 0; nj < 4; ++nj) {
                int col = wn * 64 + nj * 16 + lr;
                f32x4 v = op ? acc1[mi][nj] : acc0[mi][nj];
                float t = 0.25f * (tanh_p(v[0]) + tanh_p(v[1]) + tanh_p(v[2]) + tanh_p(v[3]));
                u16 hb = f2bf(t);
                float lo = t - bf2f(hb);
                size_t g = (size_t)p * 128 + col;
                Ch[g] = hb;
                Cl[g] = f2bf(lo);
            }
        }
    }
}

// ---------------- readout: 1x128 -> relu mlp -> scalar ----------------
__global__ __launch_bounds__(128) void readout_kernel(
    const u16* __restrict__ hH, const u16* __restrict__ hL,
    const float* __restrict__ Rw1, const float* __restrict__ Rb1,
    const float* __restrict__ Rw2, const float* __restrict__ Rb2,
    const float* __restrict__ Rw3, const float* __restrict__ Rb3,
    const float* __restrict__ Rwp, const float* __restrict__ Rbp,
    float* __restrict__ out)
{
    __shared__ float x0[HID], x1[HID], x2[HID], x3[HID], red[HID];
    const int o = threadIdx.x;

    x0[o] = bf2f(hH[o]) + bf2f(hL[o]);
    __syncthreads();

    float s = 0.f;
    for (int m = 0; m < HID; ++m) s += Rw1[o * HID + m] * x0[m];
    x1[o] = fmaxf(s + Rb1[o], 0.f);
    __syncthreads();

    s = 0.f;
    for (int m = 0; m < HID; ++m) s += Rw2[o * HID + m] * x1[m];
    x2[o] = fmaxf(s + Rb2[o], 0.f);
    __syncthreads();

    s = 0.f;
    for (int m = 0; m < HID; ++m) s += Rw3[o * HID + m] * x2[m];
    x3[o] = fmaxf(s + Rb3[o], 0.f);
    __syncthreads();

    red[o] = Rwp[o] * x3[o];
    __syncthreads();
    if (o < 64) red[o] += red[o + 64];
    __syncthreads();
    if (o == 0) {
        float t = 0.f;
        for (int i = 0; i < 64; ++i) t += red[i];
        out[0] = t + Rbp[0];
    }
}

// ---------------- host launch ----------------
extern "C" void kernel_launch(void* const* d_in, const int* in_sizes, int n_in,
                              void* d_out, int out_size, void* d_ws, size_t ws_size,
                              hipStream_t stream)
{
    const float* inputs = (const float*)d_in[0];
    const int*   ops    = (const int*)d_in[1];
    const float* W1     = (const float*)d_in[2];
    const float* W2     = (const float*)d_in[3];
    const float* W3     = (const float*)d_in[4];
    const float* Wp     = (const float*)d_in[5];
    const float* Wand   = (const float*)d_in[6];
    const float* Wor    = (const float*)d_in[7];
    const float* Rw1    = (const float*)d_in[8];
    const float* Rb1    = (const float*)d_in[9];
    const float* Rw2    = (const float*)d_in[10];
    const float* Rb2    = (const float*)d_in[11];
    const float* Rw3    = (const float*)d_in[12];
    const float* Rb3    = (const float*)d_in[13];
    const float* Rwp    = (const float*)d_in[14];
    const float* Rbp    = (const float*)d_in[15];
    float* out = (float*)d_out;
    u16* ws = (u16*)d_ws;

    // ---- workspace layout (u16 elements) ----
    size_t off = 0;
    u16* w1tH = ws + off; off += 8192;   u16* w1tL = ws + off; off += 8192;
    u16* w2tH = ws + off; off += 49152;  u16* w2tL = ws + off; off += 49152;
    u16* w3tH = ws + off; off += 98304;  u16* w3tL = ws + off; off += 98304;
    u16* wptH = ws + off; off += 32768;  u16* wptL = ws + off; off += 32768;
    u16* waH  = ws + off; off += 16384;  u16* waL  = ws + off; off += 16384;
    u16* woH  = ws + off; off += 16384;  u16* woL  = ws + off; off += 16384;
    u16* h4H  = ws + off; off += (size_t)N_LEAVES * 128;
    u16* h4L  = ws + off; off += (size_t)N_LEAVES * 128;
    u16* pA   = ws + off; off += (size_t)16384 * 128 * 2;
    u16* pB   = ws + off; off += (size_t)16384 * 128 * 2;

    // ---- weight prep ----
    wsplit_t<<<4,  256, 0, stream>>>(W1, w1tH, w1tL, 128, 64);
    wsplit_t<<<24, 256, 0, stream>>>(W2, w2tH, w2tL, 384, 128);
    wsplit_t<<<48, 256, 0, stream>>>(W3, w3tH, w3tL, 256, 384);
    wsplit_t<<<16, 256, 0, stream>>>(Wp, wptH, wptL, 128, 256);
    split_kernel<<<64, 256, 0, stream>>>(Wand, waH, waL, 16384);
    split_kernel<<<64, 256, 0, stream>>>(Wor,  woH, woL, 16384);

    // ---- fused leaf MLP ----
    leaf_fused<<<N_LEAVES / 32, 256, 0, stream>>>(
        inputs, w1tH, w1tL, w2tH, w2tL, w3tH, w3tL, wptH, wptL, h4H, h4L);

    // ---- tree reduction, level 7 down to 0 ----
    const u16* hinH = h4H;
    const u16* hinL = h4L;
    for (int lv = 7; lv >= 0; --lv) {
        int n = 1 << (2 * lv);
        int start = (n - 1) / 3;
        int Mr = n * 4;
        u16* outH = (lv & 1) ? pB : pA;
        u16* outL = outH + (size_t)n * 128;
        tree_gemm<<<dim3((Mr + 127) / 128, 1), 256, 0, stream>>>(
            hinH, hinL, waH, waL, woH, woL, ops + start,
            outH, outL, Mr, 128, 128);
        hinH = outH;
        hinL = outL;
    }

    // ---- readout ----
    readout_kernel<<<1, 128, 0, stream>>>(hinH, hinL,
        Rw1, Rb1, Rw2, Rb2, Rw3, Rb3, Rwp, Rbp, out);
}

// Round 7
// 189.573 us; speedup vs baseline: 2.0919x; 1.1851x over previous
//
#include <hip/hip_runtime.h>
#include <hip/hip_bf16.h>
#include <stdint.h>

#define N_LEAVES 65536
#define MEM 128
#define HID 128

typedef float  f32x4 __attribute__((ext_vector_type(4)));
typedef short  s16x8 __attribute__((ext_vector_type(8)));
typedef unsigned short u16;
typedef u16    u16x8 __attribute__((ext_vector_type(8)));
typedef u16    u16x4 __attribute__((ext_vector_type(4)));

__device__ __forceinline__ u16 f2bf(float x) {
    unsigned u = __builtin_bit_cast(unsigned, x);
    u += 0x7FFFu + ((u >> 16) & 1u);          // round-to-nearest-even
    return (u16)(u >> 16);
}
__device__ __forceinline__ float bf2f(u16 b) {
    unsigned u = ((unsigned)b) << 16;
    return __builtin_bit_cast(float, u);
}
// cheap tanh (leaf layers): absolute err ~1e-7, fine when vector norm is O(1)
__device__ __forceinline__ float tanh_c(float x) {
    float E = __builtin_amdgcn_exp2f(x * 2.8853900817779268f);  // exp(2x)
    return 1.0f - 2.0f * __builtin_amdgcn_rcpf(E + 1.0f);
}
// tree tanh: full RELATIVE accuracy for small |x| (deep-tree h ~ 1e-5)
__device__ __forceinline__ float tanh_p(float x) {
    float x2 = x * x;
    float poly = x * (1.0f + x2 * (-0.33333334f + x2 * 0.13333334f));
    float E = __builtin_amdgcn_exp2f(x * 2.8853900817779268f);
    float ex = 1.0f - 2.0f * __builtin_amdgcn_rcpf(E + 1.0f);
    return (__builtin_fabsf(x) < 0.25f) ? poly : ex;
}

__device__ __forceinline__ f32x4 mfma_bf(s16x8 a, s16x8 b, f32x4 c) {
    return __builtin_amdgcn_mfma_f32_16x16x32_bf16(a, b, c, 0, 0, 0);
}

// ---------------- single prep kernel: split all 6 weights ----------------
// leaf weights -> k-major fragment layout [(k/8)*N + n]*8 + (k%8), hi/lo.
// tree weights -> row-major hi/lo planes.
__global__ __launch_bounds__(256) void prep_all(
    const float* __restrict__ W1, const float* __restrict__ W2,
    const float* __restrict__ W3, const float* __restrict__ Wp,
    const float* __restrict__ Wand, const float* __restrict__ Wor,
    u16* __restrict__ w1tH, u16* __restrict__ w1tL,
    u16* __restrict__ w2tH, u16* __restrict__ w2tL,
    u16* __restrict__ w3tH, u16* __restrict__ w3tL,
    u16* __restrict__ wptH, u16* __restrict__ wptL,
    u16* __restrict__ waH,  u16* __restrict__ waL,
    u16* __restrict__ woH,  u16* __restrict__ woL)
{
    int g = blockIdx.x * 256 + threadIdx.x;    // one granule (8 elems)
    const float* W; u16 *Th, *Tl; int K, N, base; bool kmaj = true;
    if (g < 1024)       { W = W1;  Th = w1tH; Tl = w1tL; N = 128; K = 64;  base = 0; }
    else if (g < 7168)  { W = W2;  Th = w2tH; Tl = w2tL; N = 384; K = 128; base = 1024; }
    else if (g < 19456) { W = W3;  Th = w3tH; Tl = w3tL; N = 256; K = 384; base = 7168; }
    else if (g < 23552) { W = Wp;  Th = wptH; Tl = wptL; N = 128; K = 256; base = 19456; }
    else if (g < 25600) { W = Wand; Th = waH; Tl = waL;  N = 128; K = 128; base = 23552; kmaj = false; }
    else if (g < 27648) { W = Wor;  Th = woH; Tl = woL;  N = 128; K = 128; base = 25600; kmaj = false; }
    else return;
    int t = g - base;
    int kg8 = K >> 3;
    int n = t / kg8, kg = t - n * kg8;
    const float* src = &W[(size_t)n * K + kg * 8];
    size_t dst = kmaj ? ((size_t)kg * N + n) * 8 : ((size_t)n * K + kg * 8);
    u16x8 hv, lv;
    #pragma unroll
    for (int j = 0; j < 8; ++j) {
        float v = src[j];
        u16 hb = f2bf(v);
        hv[j] = hb;
        lv[j] = f2bf(v - bf2f(hb));
    }
    *(u16x8*)&Th[dst] = hv;
    *(u16x8*)&Tl[dst] = lv;
}

// act LDS addressing: 16B granules, XOR-swizzled within each row's stripe.
__device__ __forceinline__ int act_g(int Wu, int row, int c4) {
    return row * (Wu >> 3) + (c4 ^ (row & 7));   // granule index
}

// ------------- one fused MLP layer, TRANSPOSED (weights=A, acts=B) -------------
// D[feature][act-row]: lane holds 4 consecutive features of one act row ->
// packed b64 epilogue writes. FJ: 16-feature frags per wave (8 waves);
// KTN = K/32; WIN/WOUT widths in u16.
template<int FJ, int KTN, int WIN, int WOUT, bool TOGLOBAL>
__device__ __forceinline__ void mlp_layer_t(
    const u16* inH, const u16* inL,                   // LDS act planes (swizzled)
    const u16* __restrict__ BtH, const u16* __restrict__ BtL,  // global k-major W
    u16* outH, u16* outL,                             // LDS planes or global
    int gRowBase, int w, int l)
{
    const int lr = l & 15, lc = l >> 4;
    const int featBase = w * (FJ * 16);

    f32x4 acc[FJ][2] = {};
    s16x8 wh[2][FJ], wl[2][FJ];

    #pragma unroll
    for (int fi = 0; fi < FJ; ++fi) {
        size_t o = ((size_t)lc * WOUT + featBase + fi * 16 + lr) * 8;
        wh[0][fi] = *(const s16x8*)&BtH[o];
        wl[0][fi] = *(const s16x8*)&BtL[o];
    }

    #pragma unroll
    for (int kt = 0; kt < KTN; ++kt) {
        const int cur = kt & 1;
        if (kt + 1 < KTN) {
            #pragma unroll
            for (int fi = 0; fi < FJ; ++fi) {
                size_t o = ((size_t)((kt + 1) * 4 + lc) * WOUT + featBase + fi * 16 + lr) * 8;
                wh[cur ^ 1][fi] = *(const s16x8*)&BtH[o];
                wl[cur ^ 1][fi] = *(const s16x8*)&BtL[o];
            }
        }
        s16x8 ah[2], al[2];
        #pragma unroll
        for (int rj = 0; rj < 2; ++rj) {
            int off = act_g(WIN, rj * 16 + lr, kt * 4 + lc) * 8;
            ah[rj] = *(const s16x8*)&inH[off];
            al[rj] = *(const s16x8*)&inL[off];
        }
        #pragma unroll
        for (int fi = 0; fi < FJ; ++fi)
            #pragma unroll
            for (int rj = 0; rj < 2; ++rj) {
                f32x4 a = acc[fi][rj];
                a = mfma_bf(wh[cur][fi], ah[rj], a);   // hh
                a = mfma_bf(wh[cur][fi], al[rj], a);   // h*l
                a = mfma_bf(wl[cur][fi], ah[rj], a);   // l*h
                acc[fi][rj] = a;
            }
    }

    // epilogue: tanh + re-split + packed b64 store (4 consecutive features)
    #pragma unroll
    for (int fi = 0; fi < FJ; ++fi)
        #pragma unroll
        for (int rj = 0; rj < 2; ++rj) {
            int m  = rj * 16 + lr;
            int n0 = featBase + fi * 16 + lc * 4;
            f32x4 v = acc[fi][rj];
            u16x4 hv, lv;
            #pragma unroll
            for (int r = 0; r < 4; ++r) {
                float t = tanh_c(v[r]);
                u16 hb = f2bf(t);
                hv[r] = hb;
                lv[r] = f2bf(t - bf2f(hb));
            }
            if constexpr (TOGLOBAL) {
                size_t gaddr = (size_t)(gRowBase + m) * WOUT + n0;
                *(u16x4*)&outH[gaddr] = hv;
                *(u16x4*)&outL[gaddr] = lv;
            } else {
                int go = act_g(WOUT, m, n0 >> 3) * 8 + (n0 & 7);
                *(u16x4*)&outH[go] = hv;
                *(u16x4*)&outL[go] = lv;
            }
        }
}

// ---------------- fused 4-layer leaf MLP: 32 rows/block, 8 waves ----------------
__global__ __launch_bounds__(512, 4) void leaf_fused(
    const float* __restrict__ x,                 // [65536][64] fp32
    const u16* __restrict__ W1tH, const u16* __restrict__ W1tL,
    const u16* __restrict__ W2tH, const u16* __restrict__ W2tL,
    const u16* __restrict__ W3tH, const u16* __restrict__ W3tL,
    const u16* __restrict__ WptH, const u16* __restrict__ WptL,
    u16* __restrict__ h4H, u16* __restrict__ h4L)
{
    __shared__ u16 buf0[2 * 32 * 384];   // x (64) then h2 (384)
    __shared__ u16 buf1[2 * 32 * 256];   // h1 (128) then h3 (256)

    const int tid = threadIdx.x;
    const int w = tid >> 6, l = tid & 63;
    const int rowBase = blockIdx.x * 32;

    // stage x -> buf0 hi/lo planes (W=64), swizzled, packed 16B stores
    if (tid < 256) {
        int row = tid >> 3;
        int c0  = (tid & 7) * 8;
        const float* src = &x[(size_t)(rowBase + row) * 64 + c0];
        float4 v0 = *(const float4*)src;
        float4 v1 = *(const float4*)(src + 4);
        float xs[8] = {v0.x, v0.y, v0.z, v0.w, v1.x, v1.y, v1.z, v1.w};
        int go = act_g(64, row, c0 >> 3) * 8;
        u16x8 hv, lv;
        #pragma unroll
        for (int j = 0; j < 8; ++j) {
            u16 hb = f2bf(xs[j]);
            hv[j] = hb;
            lv[j] = f2bf(xs[j] - bf2f(hb));
        }
        *(u16x8*)&buf0[go] = hv;
        *(u16x8*)&buf0[32 * 64 + go] = lv;
    }
    __syncthreads();

    // L1: 64 -> 128
    mlp_layer_t<1, 2, 64, 128, false>(buf0, buf0 + 32 * 64, W1tH, W1tL,
                                      buf1, buf1 + 32 * 128, 0, w, l);
    __syncthreads();
    // L2: 128 -> 384
    mlp_layer_t<3, 4, 128, 384, false>(buf1, buf1 + 32 * 128, W2tH, W2tL,
                                       buf0, buf0 + 32 * 384, 0, w, l);
    __syncthreads();
    // L3: 384 -> 256
    mlp_layer_t<2, 12, 384, 256, false>(buf0, buf0 + 32 * 384, W3tH, W3tL,
                                        buf1, buf1 + 32 * 256, 0, w, l);
    __syncthreads();
    // L4: 256 -> 128, straight to global h4 planes
    mlp_layer_t<1, 8, 256, 128, true>(buf1, buf1 + 32 * 256, WptH, WptL,
                                      h4H, h4L, rowBase, w, l);
}

// ---------------- tree GEMM (proven round-5/6 path) ----------------
__device__ __forceinline__ int swz(int row, int ch) {
    int slot = (ch ^ (row & 3) ^ ((row >> 2) & 3)) & 3;
    return row * 32 + slot * 8;
}
__device__ __forceinline__ void gl_lds16(const void* g, void* l) {
    __builtin_amdgcn_global_load_lds(
        (const __attribute__((address_space(1))) unsigned int*)g,
        (__attribute__((address_space(3))) unsigned int*)l, 16, 0, 0);
}

__global__ __launch_bounds__(256, 2) void tree_gemm(
    const u16* __restrict__ Ah, const u16* __restrict__ Al,
    const u16* __restrict__ B0h, const u16* __restrict__ B0l,
    const u16* __restrict__ B1h, const u16* __restrict__ B1l,
    const int* __restrict__ ops,
    u16* __restrict__ Ch, u16* __restrict__ Cl,
    int M, int N, int K)
{
    __shared__ u16 sAh[4096], sAl[4096], sBh[4096], sBl[4096];
    __shared__ u16 sB2h[4096], sB2l[4096];

    const int tid = threadIdx.x;
    const int l   = tid & 63;
    const int w   = tid >> 6;
    const int wm  = w >> 1, wn = w & 1;
    const int lr  = l & 15, lc = l >> 4;
    const int bm  = blockIdx.x * 128;
    const int bn  = blockIdx.y * 128;

    const int Arows = (M - bm < 128) ? (M - bm) : 128;

    int rows[2], chs[2];
    #pragma unroll
    for (int c = 0; c < 2; ++c) {
        int g = (w * 2 + c) * 64 + l;
        int row = g >> 2;
        rows[c] = row;
        chs[c]  = (g & 3) ^ (row & 3) ^ ((row >> 2) & 3);
    }

    f32x4 acc0[4][4] = {};
    f32x4 acc1[4][4] = {};

    const int nt = K >> 5;
    for (int t = 0; t < nt; ++t) {
        #pragma unroll
        for (int c = 0; c < 2; ++c) {
            const int row = rows[c], ch = chs[c];
            const int ra  = (row < Arows) ? row : (Arows - 1);
            const int segoff = (w * 2 + c) * 512;
            size_t ga = (size_t)(bm + ra) * K + (t << 5) + ch * 8;
            size_t gb = (size_t)(bn + row) * K + (t << 5) + ch * 8;
            gl_lds16(Ah  + ga, &sAh[segoff]);
            gl_lds16(Al  + ga, &sAl[segoff]);
            gl_lds16(B0h + gb, &sBh[segoff]);
            gl_lds16(B0l + gb, &sBl[segoff]);
            gl_lds16(B1h + gb, &sB2h[segoff]);
            gl_lds16(B1l + gb, &sB2l[segoff]);
        }
        __syncthreads();

        s16x8 fah[4], fal[4];
        #pragma unroll
        for (int mi = 0; mi < 4; ++mi) {
            int so = swz(wm * 64 + mi * 16 + lr, lc);
            fah[mi] = *(const s16x8*)&sAh[so];
            fal[mi] = *(const s16x8*)&sAl[so];
        }
        #pragma unroll
        for (int nj = 0; nj < 4; ++nj) {
            int so = swz(wn * 64 + nj * 16 + lr, lc);
            s16x8 b0h = *(const s16x8*)&sBh[so];
            s16x8 b0l = *(const s16x8*)&sBl[so];
            s16x8 b1h = *(const s16x8*)&sB2h[so];
            s16x8 b1l = *(const s16x8*)&sB2l[so];
            #pragma unroll
            for (int mi = 0; mi < 4; ++mi) {
                f32x4 a = acc0[mi][nj];
                a = mfma_bf(fah[mi], b0h, a);
                a = mfma_bf(fah[mi], b0l, a);
                a = mfma_bf(fal[mi], b0h, a);
                acc0[mi][nj] = a;
                f32x4 o = acc1[mi][nj];
                o = mfma_bf(fah[mi], b1h, o);
                o = mfma_bf(fah[mi], b1l, o);
                o = mfma_bf(fal[mi], b1h, o);
                acc1[mi][nj] = o;
            }
        }
        __syncthreads();
    }

    const int P = M >> 2;
    #pragma unroll
    for (int mi = 0; mi < 4; ++mi) {
        int p = (bm >> 2) + wm * 16 + mi * 4 + lc;
        int pc = (p < P) ? p : (P - 1);
        int op = ops[pc];
        if (p < P) {
            #pragma unroll
            for (int nj = 0; nj < 4; ++nj) {
                int col = wn * 64 + nj * 16 + lr;
                f32x4 v = op ? acc1[mi][nj] : acc0[mi][nj];
                float t = 0.25f * (tanh_p(v[0]) + tanh_p(v[1]) + tanh_p(v[2]) + tanh_p(v[3]));
                u16 hb = f2bf(t);
                float lo = t - bf2f(hb);
                size_t g = (size_t)p * 128 + col;
                Ch[g] = hb;
                Cl[g] = f2bf(lo);
            }
        }
    }
}

// ---------------- readout: 1x128 -> relu mlp -> scalar ----------------
__global__ __launch_bounds__(128) void readout_kernel(
    const u16* __restrict__ hH, const u16* __restrict__ hL,
    const float* __restrict__ Rw1, const float* __restrict__ Rb1,
    const float* __restrict__ Rw2, const float* __restrict__ Rb2,
    const float* __restrict__ Rw3, const float* __restrict__ Rb3,
    const float* __restrict__ Rwp, const float* __restrict__ Rbp,
    float* __restrict__ out)
{
    __shared__ float x0[HID], x1[HID], x2[HID], x3[HID], red[HID];
    const int o = threadIdx.x;

    x0[o] = bf2f(hH[o]) + bf2f(hL[o]);
    __syncthreads();

    float s = 0.f;
    for (int m = 0; m < HID; ++m) s += Rw1[o * HID + m] * x0[m];
    x1[o] = fmaxf(s + Rb1[o], 0.f);
    __syncthreads();

    s = 0.f;
    for (int m = 0; m < HID; ++m) s += Rw2[o * HID + m] * x1[m];
    x2[o] = fmaxf(s + Rb2[o], 0.f);
    __syncthreads();

    s = 0.f;
    for (int m = 0; m < HID; ++m) s += Rw3[o * HID + m] * x2[m];
    x3[o] = fmaxf(s + Rb3[o], 0.f);
    __syncthreads();

    red[o] = Rwp[o] * x3[o];
    __syncthreads();
    if (o < 64) red[o] += red[o + 64];
    __syncthreads();
    if (o == 0) {
        float t = 0.f;
        for (int i = 0; i < 64; ++i) t += red[i];
        out[0] = t + Rbp[0];
    }
}

// ---------------- host launch ----------------
extern "C" void kernel_launch(void* const* d_in, const int* in_sizes, int n_in,
                              void* d_out, int out_size, void* d_ws, size_t ws_size,
                              hipStream_t stream)
{
    const float* inputs = (const float*)d_in[0];
    const int*   ops    = (const int*)d_in[1];
    const float* W1     = (const float*)d_in[2];
    const float* W2     = (const float*)d_in[3];
    const float* W3     = (const float*)d_in[4];
    const float* Wp     = (const float*)d_in[5];
    const float* Wand   = (const float*)d_in[6];
    const float* Wor    = (const float*)d_in[7];
    const float* Rw1    = (const float*)d_in[8];
    const float* Rb1    = (const float*)d_in[9];
    const float* Rw2    = (const float*)d_in[10];
    const float* Rb2    = (const float*)d_in[11];
    const float* Rw3    = (const float*)d_in[12];
    const float* Rb3    = (const float*)d_in[13];
    const float* Rwp    = (const float*)d_in[14];
    const float* Rbp    = (const float*)d_in[15];
    float* out = (float*)d_out;
    u16* ws = (u16*)d_ws;

    // ---- workspace layout (u16 elements) ----
    size_t off = 0;
    u16* w1tH = ws + off; off += 8192;   u16* w1tL = ws + off; off += 8192;
    u16* w2tH = ws + off; off += 49152;  u16* w2tL = ws + off; off += 49152;
    u16* w3tH = ws + off; off += 98304;  u16* w3tL = ws + off; off += 98304;
    u16* wptH = ws + off; off += 32768;  u16* wptL = ws + off; off += 32768;
    u16* waH  = ws + off; off += 16384;  u16* waL  = ws + off; off += 16384;
    u16* woH  = ws + off; off += 16384;  u16* woL  = ws + off; off += 16384;
    u16* h4H  = ws + off; off += (size_t)N_LEAVES * 128;
    u16* h4L  = ws + off; off += (size_t)N_LEAVES * 128;
    u16* pA   = ws + off; off += (size_t)16384 * 128 * 2;
    u16* pB   = ws + off; off += (size_t)16384 * 128 * 2;

    // ---- weight prep (one launch) ----
    prep_all<<<108, 256, 0, stream>>>(W1, W2, W3, Wp, Wand, Wor,
        w1tH, w1tL, w2tH, w2tL, w3tH, w3tL, wptH, wptL, waH, waL, woH, woL);

    // ---- fused leaf MLP ----
    leaf_fused<<<N_LEAVES / 32, 512, 0, stream>>>(
        inputs, w1tH, w1tL, w2tH, w2tL, w3tH, w3tL, wptH, wptL, h4H, h4L);

    // ---- tree reduction, level 7 down to 0 ----
    const u16* hinH = h4H;
    const u16* hinL = h4L;
    for (int lv = 7; lv >= 0; --lv) {
        int n = 1 << (2 * lv);
        int start = (n - 1) / 3;
        int Mr = n * 4;
        u16* outH = (lv & 1) ? pB : pA;
        u16* outL = outH + (size_t)n * 128;
        tree_gemm<<<dim3((Mr + 127) / 128, 1), 256, 0, stream>>>(
            hinH, hinL, waH, waL, woH, woL, ops + start,
            outH, outL, Mr, 128, 128);
        hinH = outH;
        hinL = outL;
    }

    // ---- readout ----
    readout_kernel<<<1, 128, 0, stream>>>(hinH, hinL,
        Rw1, Rb1, Rw2, Rb2, Rw3, Rb3, Rwp, Rbp, out);
}

// Round 8
// 155.277 us; speedup vs baseline: 2.5540x; 1.2209x over previous
//
#include <hip/hip_runtime.h>
#include <hip/hip_bf16.h>
#include <stdint.h>

#define N_LEAVES 65536
#define MEM 128
#define HID 128

typedef float  f32x4 __attribute__((ext_vector_type(4)));
typedef short  s16x8 __attribute__((ext_vector_type(8)));
typedef unsigned short u16;
typedef u16    u16x8 __attribute__((ext_vector_type(8)));

__device__ __forceinline__ u16 f2bf(float x) {
    unsigned u = __builtin_bit_cast(unsigned, x);
    u += 0x7FFFu + ((u >> 16) & 1u);          // RNE (prep only)
    return (u16)(u >> 16);
}
__device__ __forceinline__ float bf2f(u16 b) {
    unsigned u = ((unsigned)b) << 16;
    return __builtin_bit_cast(float, u);
}
// truncate-to-bf16 helpers (hi=trunc, lo captures err; combined rel ~2^-16)
__device__ __forceinline__ float hif(float x) {
    return __builtin_bit_cast(float, __builtin_bit_cast(unsigned, x) & 0xffff0000u);
}
// pack trunc-bf16 of (e0,e1) into one dword: low16=bf(e0), high16=bf(e1)
__device__ __forceinline__ unsigned packbf(float e0, float e1) {
    return __builtin_amdgcn_perm(__builtin_bit_cast(unsigned, e1),
                                 __builtin_bit_cast(unsigned, e0), 0x07060302u);
}
// cheap tanh (leaf): absolute err ~1e-7, fine for O(1)-norm activations
__device__ __forceinline__ float tanh_c(float x) {
    float E = __builtin_amdgcn_exp2f(x * 2.8853900817779268f);  // exp(2x)
    return 1.0f - 2.0f * __builtin_amdgcn_rcpf(E + 1.0f);
}
// tree tanh: full RELATIVE accuracy for small |x| (deep-tree h ~ 1e-5)
__device__ __forceinline__ float tanh_p(float x) {
    float x2 = x * x;
    float poly = x * (1.0f + x2 * (-0.33333334f + x2 * 0.13333334f));
    float E = __builtin_amdgcn_exp2f(x * 2.8853900817779268f);
    float ex = 1.0f - 2.0f * __builtin_amdgcn_rcpf(E + 1.0f);
    return (__builtin_fabsf(x) < 0.25f) ? poly : ex;
}

__device__ __forceinline__ f32x4 mfma_bf(s16x8 a, s16x8 b, f32x4 c) {
    return __builtin_amdgcn_mfma_f32_16x16x32_bf16(a, b, c, 0, 0, 0);
}

// ---------------- single prep kernel: split all 6 weights to k-major ----------------
// layout: [(k/8)*N + n]*8 + (k%8), hi/lo planes (RNE split).
__global__ __launch_bounds__(256) void prep_all(
    const float* __restrict__ W1, const float* __restrict__ W2,
    const float* __restrict__ W3, const float* __restrict__ Wp,
    const float* __restrict__ Wand, const float* __restrict__ Wor,
    u16* __restrict__ w1tH, u16* __restrict__ w1tL,
    u16* __restrict__ w2tH, u16* __restrict__ w2tL,
    u16* __restrict__ w3tH, u16* __restrict__ w3tL,
    u16* __restrict__ wptH, u16* __restrict__ wptL,
    u16* __restrict__ waH,  u16* __restrict__ waL,
    u16* __restrict__ woH,  u16* __restrict__ woL)
{
    int g = blockIdx.x * 256 + threadIdx.x;    // one granule (8 elems)
    const float* W; u16 *Th, *Tl; int K, N, base;
    if (g < 1024)       { W = W1;  Th = w1tH; Tl = w1tL; N = 128; K = 64;  base = 0; }
    else if (g < 7168)  { W = W2;  Th = w2tH; Tl = w2tL; N = 384; K = 128; base = 1024; }
    else if (g < 19456) { W = W3;  Th = w3tH; Tl = w3tL; N = 256; K = 384; base = 7168; }
    else if (g < 23552) { W = Wp;  Th = wptH; Tl = wptL; N = 128; K = 256; base = 19456; }
    else if (g < 25600) { W = Wand; Th = waH; Tl = waL;  N = 128; K = 128; base = 23552; }
    else if (g < 27648) { W = Wor;  Th = woH; Tl = woL;  N = 128; K = 128; base = 25600; }
    else return;
    int t = g - base;
    int kg8 = K >> 3;
    int n = t / kg8, kg = t - n * kg8;
    const float* src = &W[(size_t)n * K + kg * 8];
    size_t dst = ((size_t)kg * N + n) * 8;
    u16x8 hv, lv;
    #pragma unroll
    for (int j = 0; j < 8; ++j) {
        float v = src[j];
        u16 hb = f2bf(v);
        hv[j] = hb;
        lv[j] = f2bf(v - bf2f(hb));
    }
    *(u16x8*)&Th[dst] = hv;
    *(u16x8*)&Tl[dst] = lv;
}

// act LDS addressing: 16B granules, XOR-swizzled within each row's stripe.
__device__ __forceinline__ int act_g(int Wu, int row, int c4) {
    return row * (Wu >> 3) + (c4 ^ (row & 7));   // granule index
}

// ------------- one fused leaf layer, TRANSPOSED (weights=A, acts=B) -------------
template<int FJ, int KTN, int WIN, int WOUT, bool TOGLOBAL>
__device__ __forceinline__ void mlp_layer_t(
    const u16* inH, const u16* inL,                   // LDS act planes (swizzled)
    const u16* __restrict__ BtH, const u16* __restrict__ BtL,  // global k-major W
    u16* outH, u16* outL,                             // LDS planes or global
    int gRowBase, int w, int l)
{
    const int lr = l & 15, lc = l >> 4;
    const int featBase = w * (FJ * 16);

    f32x4 acc[FJ][2] = {};
    s16x8 wh[2][FJ], wl[2][FJ];

    #pragma unroll
    for (int fi = 0; fi < FJ; ++fi) {
        int o = (lc * WOUT + featBase + fi * 16 + lr) * 8;
        wh[0][fi] = *(const s16x8*)&BtH[o];
        wl[0][fi] = *(const s16x8*)&BtL[o];
    }

    #pragma unroll
    for (int kt = 0; kt < KTN; ++kt) {
        const int cur = kt & 1;
        if (kt + 1 < KTN) {
            #pragma unroll
            for (int fi = 0; fi < FJ; ++fi) {
                int o = (((kt + 1) * 4 + lc) * WOUT + featBase + fi * 16 + lr) * 8;
                wh[cur ^ 1][fi] = *(const s16x8*)&BtH[o];
                wl[cur ^ 1][fi] = *(const s16x8*)&BtL[o];
            }
        }
        s16x8 ah[2], al[2];
        #pragma unroll
        for (int rj = 0; rj < 2; ++rj) {
            int off = act_g(WIN, rj * 16 + lr, kt * 4 + lc) * 8;
            ah[rj] = *(const s16x8*)&inH[off];
            al[rj] = *(const s16x8*)&inL[off];
        }
        #pragma unroll
        for (int fi = 0; fi < FJ; ++fi)
            #pragma unroll
            for (int rj = 0; rj < 2; ++rj) {
                f32x4 a = acc[fi][rj];
                a = mfma_bf(wh[cur][fi], ah[rj], a);
                a = mfma_bf(wh[cur][fi], al[rj], a);
                a = mfma_bf(wl[cur][fi], ah[rj], a);
                acc[fi][rj] = a;
            }
    }

    // epilogue: tanh + trunc-split + perm-pack (2 dword stores per frag/plane)
    #pragma unroll
    for (int fi = 0; fi < FJ; ++fi)
        #pragma unroll
        for (int rj = 0; rj < 2; ++rj) {
            int m  = rj * 16 + lr;
            int n0 = featBase + fi * 16 + lc * 4;
            f32x4 v = acc[fi][rj];
            float t0 = tanh_c(v[0]), t1 = tanh_c(v[1]);
            float t2 = tanh_c(v[2]), t3 = tanh_c(v[3]);
            uint2 hp, lp;
            hp.x = packbf(t0, t1);
            hp.y = packbf(t2, t3);
            lp.x = packbf(t0 - hif(t0), t1 - hif(t1));
            lp.y = packbf(t2 - hif(t2), t3 - hif(t3));
            if constexpr (TOGLOBAL) {
                size_t gaddr = (size_t)(gRowBase + m) * WOUT + n0;
                *(uint2*)&outH[gaddr] = hp;
                *(uint2*)&outL[gaddr] = lp;
            } else {
                int go = act_g(WOUT, m, n0 >> 3) * 8 + (n0 & 7);
                *(uint2*)&outH[go] = hp;
                *(uint2*)&outL[go] = lp;
            }
        }
}

// ---------------- fused 4-layer leaf MLP: 32 rows/block, 8 waves ----------------
__global__ __launch_bounds__(512, 4) void leaf_fused(
    const float* __restrict__ x,                 // [65536][64] fp32
    const u16* __restrict__ W1tH, const u16* __restrict__ W1tL,
    const u16* __restrict__ W2tH, const u16* __restrict__ W2tL,
    const u16* __restrict__ W3tH, const u16* __restrict__ W3tL,
    const u16* __restrict__ WptH, const u16* __restrict__ WptL,
    u16* __restrict__ h4H, u16* __restrict__ h4L)
{
    __shared__ u16 buf0[2 * 32 * 384];   // x (64) then h2 (384)
    __shared__ u16 buf1[2 * 32 * 256];   // h1 (128) then h3 (256)

    const int tid = threadIdx.x;
    const int w = tid >> 6, l = tid & 63;
    const int rowBase = blockIdx.x * 32;

    // stage x -> buf0 hi/lo planes (W=64), swizzled, trunc-split
    if (tid < 256) {
        int row = tid >> 3;
        int c0  = (tid & 7) * 8;
        const float* src = &x[(size_t)(rowBase + row) * 64 + c0];
        float4 v0 = *(const float4*)src;
        float4 v1 = *(const float4*)(src + 4);
        float xs[8] = {v0.x, v0.y, v0.z, v0.w, v1.x, v1.y, v1.z, v1.w};
        int go = act_g(64, row, c0 >> 3) * 8;
        uint4 hp, lp;
        hp.x = packbf(xs[0], xs[1]); hp.y = packbf(xs[2], xs[3]);
        hp.z = packbf(xs[4], xs[5]); hp.w = packbf(xs[6], xs[7]);
        lp.x = packbf(xs[0] - hif(xs[0]), xs[1] - hif(xs[1]));
        lp.y = packbf(xs[2] - hif(xs[2]), xs[3] - hif(xs[3]));
        lp.z = packbf(xs[4] - hif(xs[4]), xs[5] - hif(xs[5]));
        lp.w = packbf(xs[6] - hif(xs[6]), xs[7] - hif(xs[7]));
        *(uint4*)&buf0[go] = hp;
        *(uint4*)&buf0[32 * 64 + go] = lp;
    }
    __syncthreads();

    mlp_layer_t<1, 2, 64, 128, false>(buf0, buf0 + 32 * 64, W1tH, W1tL,
                                      buf1, buf1 + 32 * 128, 0, w, l);
    __syncthreads();
    mlp_layer_t<3, 4, 128, 384, false>(buf1, buf1 + 32 * 128, W2tH, W2tL,
                                       buf0, buf0 + 32 * 384, 0, w, l);
    __syncthreads();
    mlp_layer_t<2, 12, 384, 256, false>(buf0, buf0 + 32 * 384, W3tH, W3tL,
                                        buf1, buf1 + 32 * 256, 0, w, l);
    __syncthreads();
    mlp_layer_t<1, 8, 256, 128, true>(buf1, buf1 + 32 * 256, WptH, WptL,
                                      h4H, h4L, rowBase, w, l);
}

// ---------------- one tree level (acts=A so lane's 4 D-rows = one parent) -------
// CJ child-frags, FJ feature-frags per wave; K=128 fixed.
template<int CJ, int FJ, bool TOGLOBAL>
__device__ __forceinline__ void tree_level(
    const u16* inH, const u16* inL,                   // LDS act planes, width 128
    const u16* __restrict__ wAH, const u16* __restrict__ wAL,
    const u16* __restrict__ wOH, const u16* __restrict__ wOL,  // k-major global
    const int* __restrict__ opsL,                     // indexed by local parent
    u16* outH, u16* outL,                             // LDS planes or global rows
    int outRowBase, int nValid, int cfBase, int ffBase, int l)
{
    const int lr = l & 15, lc = l >> 4;
    f32x4 accA[CJ][FJ] = {};
    f32x4 accO[CJ][FJ] = {};

    #pragma unroll
    for (int kt = 0; kt < 4; ++kt) {
        s16x8 ah[CJ], al[CJ];
        #pragma unroll
        for (int c = 0; c < CJ; ++c) {
            int off = act_g(128, (cfBase + c) * 16 + lr, kt * 4 + lc) * 8;
            ah[c] = *(const s16x8*)&inH[off];
            al[c] = *(const s16x8*)&inL[off];
        }
        #pragma unroll
        for (int f = 0; f < FJ; ++f) {
            int wo = ((kt * 4 + lc) * 128 + ffBase + f * 16 + lr) * 8;
            s16x8 bah = *(const s16x8*)&wAH[wo];
            s16x8 bal = *(const s16x8*)&wAL[wo];
            s16x8 boh = *(const s16x8*)&wOH[wo];
            s16x8 bol = *(const s16x8*)&wOL[wo];
            #pragma unroll
            for (int c = 0; c < CJ; ++c) {
                f32x4 a = accA[c][f];
                a = mfma_bf(ah[c], bah, a);
                a = mfma_bf(ah[c], bal, a);
                a = mfma_bf(al[c], bah, a);
                accA[c][f] = a;
                f32x4 o = accO[c][f];
                o = mfma_bf(ah[c], boh, o);
                o = mfma_bf(ah[c], bol, o);
                o = mfma_bf(al[c], boh, o);
                accO[c][f] = o;
            }
        }
    }

    #pragma unroll
    for (int c = 0; c < CJ; ++c) {
        int p = (cfBase + c) * 4 + lc;          // lane's parent (4 D-rows = children)
        if (p < nValid) {
            int op = opsL[p];
            #pragma unroll
            for (int f = 0; f < FJ; ++f) {
                f32x4 v = op ? accO[c][f] : accA[c][f];
                float t = 0.25f * (tanh_p(v[0]) + tanh_p(v[1]) + tanh_p(v[2]) + tanh_p(v[3]));
                unsigned bits = __builtin_bit_cast(unsigned, t);
                u16 hb = (u16)(bits >> 16);
                float lof = t - __builtin_bit_cast(float, bits & 0xffff0000u);
                u16 lb = (u16)(__builtin_bit_cast(unsigned, lof) >> 16);
                int feat = ffBase + f * 16 + lr;
                if constexpr (TOGLOBAL) {
                    int ga = (outRowBase + p) * 128 + feat;
                    outH[ga] = hb;
                    outL[ga] = lb;
                } else {
                    int go = act_g(128, p, feat >> 3) * 8 + (feat & 7);
                    outH[go] = hb;
                    outL[go] = lb;
                }
            }
        }
    }
}

// ---------------- fused 3-level tree kernel: 128 child rows -> 2 parents --------
__global__ __launch_bounds__(512, 4) void tree3(
    const u16* __restrict__ inH, const u16* __restrict__ inL,   // [blocks*128][128]
    const u16* __restrict__ wAH, const u16* __restrict__ wAL,
    const u16* __restrict__ wOH, const u16* __restrict__ wOL,
    const int* __restrict__ ops0, const int* __restrict__ ops1,
    const int* __restrict__ ops2,
    u16* __restrict__ outH, u16* __restrict__ outL)             // [blocks*2][128]
{
    __shared__ u16 L0H[16384], L0L[16384];   // 128 rows (reused by level c out)
    __shared__ u16 L1H[4096],  L1L[4096];    // 32 rows

    const int tid = threadIdx.x;
    const int w = tid >> 6, l = tid & 63;
    const int blk = blockIdx.x;

    // stage 128 rows x 128 cols hi/lo, swizzled
    #pragma unroll
    for (int it = 0; it < 4; ++it) {
        int g = tid + it * 512;              // granule 0..2047
        int row = g >> 4, c4 = g & 15;
        size_t src = (size_t)(blk * 128 + row) * 128 + c4 * 8;
        int dst = act_g(128, row, c4) * 8;
        *(u16x8*)&L0H[dst] = *(const u16x8*)&inH[src];
        *(u16x8*)&L0L[dst] = *(const u16x8*)&inL[src];
    }
    __syncthreads();

    // level a: 128 rows -> 32 parents
    tree_level<2, 4, false>(L0H, L0L, wAH, wAL, wOH, wOL, ops0 + blk * 32,
                            L1H, L1L, 0, 32, (w & 3) * 2, (w >> 2) * 64, l);
    __syncthreads();
    // level b: 32 rows -> 8 parents (into L0 region, rows 0..7)
    tree_level<1, 2, false>(L1H, L1L, wAH, wAL, wOH, wOL, ops1 + blk * 8,
                            L0H, L0L, 0, 8, (w >> 2), (w & 3) * 32, l);
    __syncthreads();
    // level c: 8 rows (padded frag) -> 2 parents, to global
    tree_level<1, 1, true>(L0H, L0L, wAH, wAL, wOH, wOL, ops2 + blk * 2,
                           outH, outL, blk * 2, 2, 0, w * 16, l);
}

// ---------------- tail: levels 1,0 + readout (fp32, float4 dots) ----------------
__global__ __launch_bounds__(256) void tail_kernel(
    const u16* __restrict__ h2H, const u16* __restrict__ h2L,   // [16][128]
    const int* __restrict__ ops,
    const float* __restrict__ Wand, const float* __restrict__ Wor,
    const float* __restrict__ Rw1, const float* __restrict__ Rb1,
    const float* __restrict__ Rw2, const float* __restrict__ Rb2,
    const float* __restrict__ Rw3, const float* __restrict__ Rb3,
    const float* __restrict__ Rwp, const float* __restrict__ Rbp,
    float* __restrict__ out)
{
    __shared__ float H[16 * 128];
    __shared__ float P[4 * 128];
    __shared__ float R[128], X1[128], X2[128], X3[128];
    const int tid = threadIdx.x;

    for (int i = tid; i < 2048; i += 256) H[i] = bf2f(h2H[i]) + bf2f(h2L[i]);
    __syncthreads();

    // level 1: 4 parents (ops[1..4])
    for (int idx = tid; idx < 512; idx += 256) {
        int p = idx >> 7, o = idx & 127;
        const float* Wsel = (ops[1 + p] == 0) ? Wand : Wor;
        const float4* wr = (const float4*)&Wsel[o * 128];
        const float4* h0 = (const float4*)&H[(p * 4 + 0) * 128];
        const float4* h1 = (const float4*)&H[(p * 4 + 1) * 128];
        const float4* h2 = (const float4*)&H[(p * 4 + 2) * 128];
        const float4* h3 = (const float4*)&H[(p * 4 + 3) * 128];
        float s0 = 0, s1 = 0, s2 = 0, s3 = 0;
        for (int m = 0; m < 32; ++m) {
            float4 wv = wr[m];
            float4 a0 = h0[m], a1 = h1[m], a2 = h2[m], a3 = h3[m];
            s0 += wv.x*a0.x + wv.y*a0.y + wv.z*a0.z + wv.w*a0.w;
            s1 += wv.x*a1.x + wv.y*a1.y + wv.z*a1.z + wv.w*a1.w;
            s2 += wv.x*a2.x + wv.y*a2.y + wv.z*a2.z + wv.w*a2.w;
            s3 += wv.x*a3.x + wv.y*a3.y + wv.z*a3.z + wv.w*a3.w;
        }
        P[idx] = 0.25f * (tanh_p(s0) + tanh_p(s1) + tanh_p(s2) + tanh_p(s3));
    }
    __syncthreads();

    // level 0: root (ops[0])
    if (tid < 128) {
        int o = tid;
        const float* Wsel = (ops[0] == 0) ? Wand : Wor;
        const float4* wr = (const float4*)&Wsel[o * 128];
        const float4* h0 = (const float4*)&P[0];
        const float4* h1 = (const float4*)&P[128];
        const float4* h2 = (const float4*)&P[256];
        const float4* h3 = (const float4*)&P[384];
        float s0 = 0, s1 = 0, s2 = 0, s3 = 0;
        for (int m = 0; m < 32; ++m) {
            float4 wv = wr[m];
            float4 a0 = h0[m], a1 = h1[m], a2 = h2[m], a3 = h3[m];
            s0 += wv.x*a0.x + wv.y*a0.y + wv.z*a0.z + wv.w*a0.w;
            s1 += wv.x*a1.x + wv.y*a1.y + wv.z*a1.z + wv.w*a1.w;
            s2 += wv.x*a2.x + wv.y*a2.y + wv.z*a2.z + wv.w*a2.w;
            s3 += wv.x*a3.x + wv.y*a3.y + wv.z*a3.z + wv.w*a3.w;
        }
        R[o] = 0.25f * (tanh_p(s0) + tanh_p(s1) + tanh_p(s2) + tanh_p(s3));
    }
    __syncthreads();

    if (tid < 128) {
        const float4* wr = (const float4*)&Rw1[tid * 128];
        const float4* xr = (const float4*)&R[0];
        float s = 0;
        for (int m = 0; m < 32; ++m) {
            float4 wv = wr[m], xv = xr[m];
            s += wv.x*xv.x + wv.y*xv.y + wv.z*xv.z + wv.w*xv.w;
        }
        X1[tid] = fmaxf(s + Rb1[tid], 0.f);
    }
    __syncthreads();
    if (tid < 128) {
        const float4* wr = (const float4*)&Rw2[tid * 128];
        const float4* xr = (const float4*)&X1[0];
        float s = 0;
        for (int m = 0; m < 32; ++m) {
            float4 wv = wr[m], xv = xr[m];
            s += wv.x*xv.x + wv.y*xv.y + wv.z*xv.z + wv.w*xv.w;
        }
        X2[tid] = fmaxf(s + Rb2[tid], 0.f);
    }
    __syncthreads();
    if (tid < 128) {
        const float4* wr = (const float4*)&Rw3[tid * 128];
        const float4* xr = (const float4*)&X2[0];
        float s = 0;
        for (int m = 0; m < 32; ++m) {
            float4 wv = wr[m], xv = xr[m];
            s += wv.x*xv.x + wv.y*xv.y + wv.z*xv.z + wv.w*xv.w;
        }
        X3[tid] = fmaxf(s + Rb3[tid], 0.f) * Rwp[tid];
    }
    __syncthreads();
    if (tid == 0) {
        float t = 0.f;
        for (int i = 0; i < 128; ++i) t += X3[i];
        out[0] = t + Rbp[0];
    }
}

// ---------------- host launch ----------------
extern "C" void kernel_launch(void* const* d_in, const int* in_sizes, int n_in,
                              void* d_out, int out_size, void* d_ws, size_t ws_size,
                              hipStream_t stream)
{
    const float* inputs = (const float*)d_in[0];
    const int*   ops    = (const int*)d_in[1];
    const float* W1     = (const float*)d_in[2];
    const float* W2     = (const float*)d_in[3];
    const float* W3     = (const float*)d_in[4];
    const float* Wp     = (const float*)d_in[5];
    const float* Wand   = (const float*)d_in[6];
    const float* Wor    = (const float*)d_in[7];
    const float* Rw1    = (const float*)d_in[8];
    const float* Rb1    = (const float*)d_in[9];
    const float* Rw2    = (const float*)d_in[10];
    const float* Rb2    = (const float*)d_in[11];
    const float* Rw3    = (const float*)d_in[12];
    const float* Rb3    = (const float*)d_in[13];
    const float* Rwp    = (const float*)d_in[14];
    const float* Rbp    = (const float*)d_in[15];
    float* out = (float*)d_out;
    u16* ws = (u16*)d_ws;

    // ---- workspace layout (u16 elements) ----
    size_t off = 0;
    u16* w1tH = ws + off; off += 8192;   u16* w1tL = ws + off; off += 8192;
    u16* w2tH = ws + off; off += 49152;  u16* w2tL = ws + off; off += 49152;
    u16* w3tH = ws + off; off += 98304;  u16* w3tL = ws + off; off += 98304;
    u16* wptH = ws + off; off += 32768;  u16* wptL = ws + off; off += 32768;
    u16* waH  = ws + off; off += 16384;  u16* waL  = ws + off; off += 16384;
    u16* woH  = ws + off; off += 16384;  u16* woL  = ws + off; off += 16384;
    u16* h4H  = ws + off; off += (size_t)N_LEAVES * 128;
    u16* h4L  = ws + off; off += (size_t)N_LEAVES * 128;
    u16* l5H  = ws + off; off += 1024 * 128;
    u16* l5L  = ws + off; off += 1024 * 128;
    u16* l2H  = ws + off; off += 16 * 128;
    u16* l2L  = ws + off; off += 16 * 128;

    // ---- weight prep ----
    prep_all<<<108, 256, 0, stream>>>(W1, W2, W3, Wp, Wand, Wor,
        w1tH, w1tL, w2tH, w2tL, w3tH, w3tL, wptH, wptL, waH, waL, woH, woL);

    // ---- fused leaf MLP ----
    leaf_fused<<<N_LEAVES / 32, 512, 0, stream>>>(
        inputs, w1tH, w1tL, w2tH, w2tL, w3tH, w3tL, wptH, wptL, h4H, h4L);

    // ---- tree levels 7,6,5 (512 blocks) ----
    tree3<<<512, 512, 0, stream>>>(h4H, h4L, waH, waL, woH, woL,
        ops + 5461, ops + 1365, ops + 341, l5H, l5L);

    // ---- tree levels 4,3,2 (8 blocks) ----
    tree3<<<8, 512, 0, stream>>>(l5H, l5L, waH, waL, woH, woL,
        ops + 85, ops + 21, ops + 5, l2H, l2L);

    // ---- levels 1,0 + readout ----
    tail_kernel<<<1, 256, 0, stream>>>(l2H, l2L, ops, Wand, Wor,
        Rw1, Rb1, Rw2, Rb2, Rw3, Rb3, Rwp, Rbp, out);
}